// Round 4
// baseline (2547.428 us; speedup 1.0000x reference)
//
#include <hip/hip_runtime.h>
#include <hip/hip_fp16.h>

#define N_NODES 65536
#define N_EDGES 2097152
#define NB      1024
#define FXD     78
#define DIM     32
#define EMBD    128
#define OUTD    128
#define VOCAB   26
#define PLEN    1000
#define KS      8
#define CLEN    121      // EMBD-KS+1
#define NF      32
#define FCX     (NF*CLEN)  // 3872
#define NBKT    256
#define EPB     8192     // edges per bucketA block (N_EDGES/256)

// ---------------- bucket sort (dst>>8) ----------------

__global__ __launch_bounds__(256) void k_bhist(
    const int* __restrict__ ei, int* __restrict__ bktCnt)
{
    __shared__ int h[NBKT];
    int tid = threadIdx.x;
    h[tid] = 0;
    __syncthreads();
    int base = blockIdx.x*1024;
    #pragma unroll
    for (int q=0; q<4; ++q) {
        int d = ei[N_EDGES + base + q*256 + tid];
        atomicAdd(&h[d>>8], 1);
    }
    __syncthreads();
    atomicAdd(&bktCnt[tid], h[tid]);
}

__global__ __launch_bounds__(256) void k_bscan(
    const int* __restrict__ bktCnt, int* __restrict__ bktBase, int* __restrict__ bktCur)
{
    __shared__ int s[NBKT];
    int t = threadIdx.x;
    int v = bktCnt[t];
    s[t] = v;
    __syncthreads();
    for (int off=1; off<256; off<<=1) {
        int tv = (t >= off) ? s[t-off] : 0;
        __syncthreads();
        s[t] += tv;
        __syncthreads();
    }
    int ex = s[t] - v;
    bktBase[t] = ex;
    bktCur[t] = ex;
    if (t == 255) bktBase[256] = s[255];   // == N_EDGES
}

// LDS-sort 8192 edges by bucket, write packed (dst<<16|src) in coalesced runs
__global__ __launch_bounds__(256) void k_bucketA(
    const int* __restrict__ ei, int* __restrict__ bktCur, unsigned int* __restrict__ pairs)
{
    __shared__ unsigned int raw[EPB];       // 32 KB
    __shared__ unsigned int srt[EPB];       // 32 KB
    __shared__ unsigned char bOf[EPB];      // 8 KB
    __shared__ int hist[NBKT], sc[NBKT], lcur[NBKT], gbase[NBKT];
    int tid = threadIdx.x;
    hist[tid] = 0;
    __syncthreads();
    int eb = blockIdx.x * EPB;
    for (int i=tid; i<EPB; i+=256) {
        int s = ei[eb+i];
        int d = ei[N_EDGES+eb+i];
        raw[i] = ((unsigned int)d<<16) | (unsigned int)s;
        atomicAdd(&hist[d>>8], 1);
    }
    __syncthreads();
    int v = hist[tid];
    sc[tid] = v;
    __syncthreads();
    for (int off=1; off<256; off<<=1) {
        int tv = (tid >= off) ? sc[tid-off] : 0;
        __syncthreads();
        sc[tid] += tv;
        __syncthreads();
    }
    int ex = sc[tid] - v;
    sc[tid] = ex;            // exclusive local base
    lcur[tid] = ex;
    gbase[tid] = atomicAdd(&bktCur[tid], v);
    __syncthreads();
    for (int i=tid; i<EPB; i+=256) {
        unsigned int p = raw[i];
        int k = p >> 24;
        int pos = atomicAdd(&lcur[k], 1);
        srt[pos] = p;
        bOf[pos] = (unsigned char)k;
    }
    __syncthreads();
    for (int i=tid; i<EPB; i+=256) {
        int k = bOf[i];
        pairs[gbase[k] + (i - sc[k])] = srt[i];
    }
}

// ---------------- GIN layer kernels ----------------

// Layer-1 transform: t = x @ w1a  (fp16 out)
__global__ __launch_bounds__(256) void k_l1_transform(
    const float* __restrict__ x, const float* __restrict__ w,
    __half* __restrict__ t)
{
    __shared__ float wS[FXD*DIM];
    for (int i = threadIdx.x; i < FXD*DIM; i += 256) wS[i] = w[i];
    __syncthreads();
    int node = blockIdx.x*256 + threadIdx.x;
    float acc[DIM];
    #pragma unroll
    for (int d=0; d<DIM; ++d) acc[d] = 0.f;
    const float* xr = x + (long)node*FXD;
    for (int j=0; j<FXD; ++j) {
        float xv = xr[j];
        #pragma unroll
        for (int d=0; d<DIM; ++d) acc[d] += xv * wS[j*DIM+d];
    }
    union { __half2 h2[16]; uint4 u4[4]; } pk;
    #pragma unroll
    for (int q=0; q<16; ++q) pk.h2[q] = __floats2half2_rn(acc[2*q], acc[2*q+1]);
    uint4* dst4 = (uint4*)(t + (long)node*DIM);
    #pragma unroll
    for (int q=0; q<4; ++q) dst4[q] = pk.u4[q];
}

// Layers 2-5: h = BN(z) via scale/shift; t = h @ w  (fp16 out)
__global__ __launch_bounds__(256) void k_transform(
    const float* __restrict__ z, const float* __restrict__ ss,
    const float* __restrict__ w, __half* __restrict__ t)
{
    __shared__ float wS[DIM*DIM];
    __shared__ float sS[2*DIM];
    for (int i = threadIdx.x; i < DIM*DIM; i += 256) wS[i] = w[i];
    if (threadIdx.x < 2*DIM) sS[threadIdx.x] = ss[threadIdx.x];
    __syncthreads();
    int node = blockIdx.x*256 + threadIdx.x;
    float h[DIM];
    const float4* z4 = (const float4*)(z + (long)node*DIM);
    #pragma unroll
    for (int q=0; q<DIM/4; ++q) {
        float4 v = z4[q];
        h[q*4+0]=v.x; h[q*4+1]=v.y; h[q*4+2]=v.z; h[q*4+3]=v.w;
    }
    #pragma unroll
    for (int d=0; d<DIM; ++d) h[d] = h[d]*sS[d] + sS[DIM+d];
    float acc[DIM];
    #pragma unroll
    for (int d=0; d<DIM; ++d) acc[d] = 0.f;
    #pragma unroll
    for (int j=0; j<DIM; ++j) {
        float hv = h[j];
        #pragma unroll
        for (int d=0; d<DIM; ++d) acc[d] += hv * wS[j*DIM+d];
    }
    union { __half2 h2[16]; uint4 u4[4]; } pk;
    #pragma unroll
    for (int q=0; q<16; ++q) pk.h2[q] = __floats2half2_rn(acc[2*q], acc[2*q+1]);
    uint4* dst4 = (uint4*)(t + (long)node*DIM);
    #pragma unroll
    for (int q=0; q<4; ++q) dst4[q] = pk.u4[q];
}

// Fused: bucket aggregate (LDS tile) + self + MLP + ReLU + BN-stats.
// One block per bucket (256 nodes). 1024 threads = 32 edge-groups of 32 lanes.
__global__ __launch_bounds__(1024) void k_agg_mlp(
    const int* __restrict__ bktBase, const unsigned int* __restrict__ pairs,
    const __half* __restrict__ t,
    const float* __restrict__ bi, const float* __restrict__ wo, const float* __restrict__ bo,
    float* __restrict__ z, float* __restrict__ part)
{
    __shared__ float acc[256*DIM];   // 32 KB
    __shared__ float wS[DIM*DIM];
    __shared__ float bS[2*DIM];
    __shared__ float stS[2*DIM];
    int tid = threadIdx.x;
    int grp = tid >> 5;
    int c = tid & 31;
    if (tid < DIM*DIM) wS[tid] = wo[tid];
    if (tid < DIM) bS[tid] = bi[tid];
    else if (tid < 2*DIM) bS[tid] = bo[tid-DIM];
    if (tid < 2*DIM) stS[tid] = 0.f;
    int node0 = blockIdx.x * 256;
    // init accumulator with self term (coalesced fp16 read)
    for (int i=tid; i<256*DIM; i+=1024)
        acc[i] = __half2float(t[(long)node0*DIM + i]);
    __syncthreads();
    int base = bktBase[blockIdx.x];
    int cnt  = bktBase[blockIdx.x+1] - base;
    for (int i=grp; i<cnt; i+=32) {
        unsigned int p = pairs[base+i];
        int src = p & 0xFFFF;
        int dl  = (p >> 16) & 0xFF;
        float v = __half2float(t[(long)src*DIM + c]);
        atomicAdd(&acc[dl*DIM + c], v);
    }
    __syncthreads();
    // MLP over 256 nodes: 32 node-groups x 8 passes
    #pragma unroll
    for (int pass=0; pass<8; ++pass) {
        int nl = grp + pass*32;
        float u = fmaxf(acc[nl*DIM + c] + bS[c], 0.f);
        float zz = bS[DIM+c];
        #pragma unroll
        for (int j=0; j<DIM; ++j)
            zz += __shfl(u, j, 32) * wS[j*DIM+c];
        zz = fmaxf(zz, 0.f);
        z[(long)(node0+nl)*DIM + c] = zz;
        float zs = zz + __shfl_down(zz, 32, 64);
        float zq = zz*zz;
        zq = zq + __shfl_down(zq, 32, 64);
        if ((tid & 63) < 32) {
            atomicAdd(&stS[c], zs);
            atomicAdd(&stS[DIM+c], zq);
        }
    }
    __syncthreads();
    if (tid < 2*DIM)
        part[(blockIdx.x << 6) + tid] = stS[tid];   // unique slice: plain store
}

// reduce partial stats -> scale/shift
__global__ __launch_bounds__(256) void k_scaleshift(
    const float* __restrict__ part,
    const float* __restrict__ gamma, const float* __restrict__ beta,
    int layer, float* __restrict__ ss)
{
    __shared__ float red[4][64];
    __shared__ float totS[64];
    int t = threadIdx.x;
    int ch = t & 63, q = t >> 6;
    float s = 0.f;
    for (int i = q*64; i < q*64 + 64; ++i) s += part[(i<<6) + ch];
    red[q][ch] = s;
    __syncthreads();
    if (t < 64) totS[t] = red[0][t]+red[1][t]+red[2][t]+red[3][t];
    __syncthreads();
    if (t < DIM) {
        float mean = totS[t] * (1.f/N_NODES);
        float var  = totS[DIM+t] * (1.f/N_NODES) - mean*mean;
        float sc = gamma[layer*DIM+t] * rsqrtf(var + 1e-5f);
        ss[t] = sc;
        ss[DIM+t] = beta[layer*DIM+t] - mean*sc;
    }
}

// Global add pool with BN applied: hg[batch[n]] += BN(z[n])
__global__ __launch_bounds__(256) void k_pool(
    const float* __restrict__ z, const float* __restrict__ ss,
    const int* __restrict__ batch, float* __restrict__ hg)
{
    long g = (long)blockIdx.x*256 + threadIdx.x;
    int node = (int)(g >> 5);
    int c = (int)(g & 31);
    int b = batch[node];
    float v = z[(long)node*DIM + c]*ss[c] + ss[DIM+c];
    atomicAdd(&hg[b*DIM + c], v);
}

// xd = ReLU(hg @ w_fcxd + b) -> xc[:, 0:128]
__global__ __launch_bounds__(128) void k_xd(
    const float* __restrict__ hg, const float* __restrict__ w,
    const float* __restrict__ bias, float* __restrict__ xc)
{
    int b = blockIdx.x, n = threadIdx.x;
    __shared__ float hS[DIM];
    if (n < DIM) hS[n] = hg[b*DIM+n];
    __syncthreads();
    float acc = bias[n];
    #pragma unroll
    for (int r=0; r<DIM; ++r) acc += hS[r]*w[r*OUTD+n];
    xc[b*256 + n] = fmaxf(acc, 0.f);
}

// ---------------- protein branch ----------------

__global__ __launch_bounds__(256) void k_cw_transpose(
    const float* __restrict__ cw, float* __restrict__ cwT)
{
    int g = blockIdx.x*256 + threadIdx.x;   // 256000 total
    int i = g >> 8;
    int j = g & 255;
    int o = j >> 3, k = j & 7;
    cwT[g] = cw[o*(PLEN*KS) + i*KS + k];
}

__global__ __launch_bounds__(256) void k_conv(
    const int* __restrict__ target, const float* __restrict__ emb,
    const float* __restrict__ cwT, const float* __restrict__ conv_b,
    float* __restrict__ c)
{
    __shared__ float embS[VOCAB*EMBD + 8];
    __shared__ float Gs[VOCAB*256];
    __shared__ int   sortedS[PLEN];
    __shared__ int   cntS[VOCAB];
    __shared__ int   segS[VOCAB+1];
    __shared__ int   curS[VOCAB];
    __shared__ float cbS[NF];
    int b = blockIdx.x, j = threadIdx.x;
    for (int i=j; i<VOCAB*EMBD; i+=256) embS[i] = emb[i];
    if (j < VOCAB) cntS[j] = 0;
    if (j < NF) cbS[j] = conv_b[j];
    __syncthreads();
    int tloc[4];
    #pragma unroll
    for (int q=0; q<4; ++q) {
        int i = j + q*256;
        if (i < PLEN) {
            tloc[q] = target[b*PLEN+i];
            atomicAdd(&cntS[tloc[q]], 1);
        } else tloc[q] = -1;
    }
    __syncthreads();
    if (j == 0) {
        int run = 0;
        for (int v=0; v<VOCAB; ++v) { segS[v]=run; run += cntS[v]; }
        segS[VOCAB] = run;
    }
    __syncthreads();
    if (j < VOCAB) curS[j] = segS[j];
    __syncthreads();
    #pragma unroll
    for (int q=0; q<4; ++q) {
        int i = j + q*256;
        if (i < PLEN) {
            int pos = atomicAdd(&curS[tloc[q]], 1);
            sortedS[pos] = i;
        }
    }
    __syncthreads();
    for (int v=0; v<VOCAB; ++v) {
        int s = segS[v], e2 = segS[v+1];
        float acc = 0.f;
        int p = s;
        for (; p+4 <= e2; p += 4) {
            int i0=sortedS[p], i1=sortedS[p+1], i2=sortedS[p+2], i3=sortedS[p+3];
            acc += cwT[i0*256+j] + cwT[i1*256+j] + cwT[i2*256+j] + cwT[i3*256+j];
        }
        for (; p<e2; ++p) acc += cwT[sortedS[p]*256+j];
        Gs[v*256+j] = acc;
    }
    __syncthreads();
    int o = j >> 3, pg = j & 7;
    int t0 = pg*16;
    int tcnt = (t0+16 <= CLEN) ? 16 : (CLEN - t0);   // 16 or 9
    float out[16];
    #pragma unroll
    for (int q=0; q<16; ++q) out[q] = cbS[o];
    for (int v=0; v<VOCAB; ++v) {
        float g[KS];
        #pragma unroll
        for (int k=0; k<KS; ++k) g[k] = Gs[v*256 + o*KS + k];
        float e[23];
        const float* ev = &embS[v*EMBD + t0];
        #pragma unroll
        for (int m=0; m<23; ++m) e[m] = ev[m];
        #pragma unroll
        for (int q=0; q<16; ++q) {
            float s = 0.f;
            #pragma unroll
            for (int k=0; k<KS; ++k) s += e[q+k]*g[k];
            out[q] += s;
        }
    }
    __syncthreads();
    float* stage = Gs;
    for (int q=0; q<tcnt; ++q) stage[o*CLEN + t0 + q] = out[q];
    __syncthreads();
    for (int idx=j; idx<FCX; idx+=256)
        c[(long)b*FCX + idx] = stage[idx];
}

// xt: [1024 x 3872] @ [3872 x 128] tiled GEMM with 8-way K-split.
#define XT_KSL 484
#define XT_BK  44
__global__ __launch_bounds__(256) void k_xt(
    const float* __restrict__ c, const float* __restrict__ w,
    const float* __restrict__ bias, float* __restrict__ xc)
{
    __shared__ float cS[32][XT_BK];
    __shared__ float wS[XT_BK][128];
    int b0 = blockIdx.x * 32;
    int ks0 = blockIdx.y * XT_KSL;
    int tid = threadIdx.x;
    int cg = tid >> 5;          // graph group 0..7
    int co = tid & 31;          // col group 0..31
    float acc[4][4];
    #pragma unroll
    for (int i2=0;i2<4;++i2)
      #pragma unroll
      for (int j2=0;j2<4;++j2) acc[i2][j2]=0.f;
    for (int ch=0; ch<11; ++ch) {
        int k0 = ks0 + ch*XT_BK;
        for (int idx=tid; idx<32*XT_BK; idx+=256) {
            int g = idx / XT_BK, kk = idx - g*XT_BK;
            cS[g][kk] = c[(long)(b0+g)*FCX + k0 + kk];
        }
        for (int idx=tid; idx<XT_BK*128; idx+=256) {
            int kk = idx >> 7, n = idx & 127;
            wS[kk][n] = w[(long)(k0+kk)*OUTD + n];
        }
        __syncthreads();
        #pragma unroll 4
        for (int kk=0; kk<XT_BK; ++kk) {
            float cv[4], wv[4];
            #pragma unroll
            for (int q=0;q<4;++q) cv[q] = cS[cg*4+q][kk];
            #pragma unroll
            for (int p=0;p<4;++p) wv[p] = wS[kk][co*4+p];
            #pragma unroll
            for (int q=0;q<4;++q)
              #pragma unroll
              for (int p=0;p<4;++p) acc[q][p] += cv[q]*wv[p];
        }
        __syncthreads();
    }
    #pragma unroll
    for (int q=0;q<4;++q) {
        int g = b0 + cg*4 + q;
        #pragma unroll
        for (int p=0;p<4;++p) {
            int n = co*4 + p;
            float v = acc[q][p];
            if (blockIdx.y == 0) v += bias[n];
            atomicAdd(&xc[g*256 + 128 + n], v);
        }
    }
}

// ---------------- joint head ----------------

__global__ __launch_bounds__(256) void k_fc1(
    const float* __restrict__ xc, const float* __restrict__ w,
    const float* __restrict__ bias, float* __restrict__ y)
{
    __shared__ float xS[4][256];
    int b0 = blockIdx.x*4, n = threadIdx.x;
    #pragma unroll
    for (int q=0; q<4; ++q) xS[q][n] = xc[(b0+q)*256 + n];
    __syncthreads();
    float acc[4][4];
    #pragma unroll
    for (int m=0; m<4; ++m) {
        float bv = bias[m*256+n];
        #pragma unroll
        for (int q=0; q<4; ++q) acc[q][m] = bv;
    }
    for (int r=0; r<256; ++r) {
        float x0=xS[0][r], x1=xS[1][r], x2=xS[2][r], x3=xS[3][r];
        #pragma unroll
        for (int m=0; m<4; ++m) {
            float wv = w[r*1024 + m*256 + n];
            acc[0][m]+=x0*wv; acc[1][m]+=x1*wv; acc[2][m]+=x2*wv; acc[3][m]+=x3*wv;
        }
    }
    #pragma unroll
    for (int q=0; q<4; ++q)
        #pragma unroll
        for (int m=0; m<4; ++m)
            y[(b0+q)*1024 + m*256 + n] = fmaxf(acc[q][m], 0.f);
}

__global__ __launch_bounds__(256) void k_fc2(
    const float* __restrict__ y, const float* __restrict__ w,
    const float* __restrict__ bias, float* __restrict__ y2)
{
    __shared__ float xS[4][1024];
    int b0 = blockIdx.x*4, n = threadIdx.x;
    #pragma unroll
    for (int q=0; q<4; ++q)
        for (int i=n; i<1024; i+=256) xS[q][i] = y[(b0+q)*1024 + i];
    __syncthreads();
    float acc[4];
    #pragma unroll
    for (int q=0; q<4; ++q) acc[q] = bias[n];
    for (int r=0; r<1024; ++r) {
        float wv = w[r*256 + n];
        #pragma unroll
        for (int q=0; q<4; ++q) acc[q] += xS[q][r]*wv;
    }
    #pragma unroll
    for (int q=0; q<4; ++q) y2[(b0+q)*256 + n] = fmaxf(acc[q], 0.f);
}

__global__ __launch_bounds__(256) void k_out(
    const float* __restrict__ y2, const float* __restrict__ w,
    const float* __restrict__ bias, float* __restrict__ out)
{
    int b = blockIdx.x, n = threadIdx.x;
    float v = y2[b*256 + n] * w[n];
    #pragma unroll
    for (int off=32; off; off>>=1) v += __shfl_down(v, off, 64);
    __shared__ float red[4];
    if ((n & 63) == 0) red[n >> 6] = v;
    __syncthreads();
    if (n == 0) out[b] = red[0]+red[1]+red[2]+red[3] + bias[0];
}

// ---------------- launch ----------------

extern "C" void kernel_launch(void* const* d_in, const int* in_sizes, int n_in,
                              void* d_out, int out_size, void* d_ws, size_t ws_size,
                              hipStream_t stream) {
    const float* x      = (const float*)d_in[0];
    const int*   ei     = (const int*)  d_in[1];
    const int*   batch  = (const int*)  d_in[2];
    const int*   target = (const int*)  d_in[3];
    const float* w1a    = (const float*)d_in[4];
    const float* b1a    = (const float*)d_in[5];
    const float* w1b    = (const float*)d_in[6];
    const float* b1b    = (const float*)d_in[7];
    const float* wa     = (const float*)d_in[8];
    const float* ba     = (const float*)d_in[9];
    const float* wb     = (const float*)d_in[10];
    const float* bb     = (const float*)d_in[11];
    const float* gamma  = (const float*)d_in[12];
    const float* beta   = (const float*)d_in[13];
    const float* w_fcxd = (const float*)d_in[14];
    const float* b_fcxd = (const float*)d_in[15];
    const float* emb    = (const float*)d_in[16];
    const float* conv_w = (const float*)d_in[17];
    const float* conv_b = (const float*)d_in[18];
    const float* w_fcxt = (const float*)d_in[19];
    const float* b_fcxt = (const float*)d_in[20];
    const float* w_fc1  = (const float*)d_in[21];
    const float* b_fc1  = (const float*)d_in[22];
    const float* w_fc2  = (const float*)d_in[23];
    const float* b_fc2  = (const float*)d_in[24];
    const float* w_out  = (const float*)d_in[25];
    const float* b_out  = (const float*)d_in[26];

    float* ws      = (float*)d_ws;
    __half* tH     = (__half*)ws;                          // N*32 halfs = 1,048,576 float-slots
    float* z       = ws + 1048576;                         // N*32 floats
    unsigned int* pairs = (unsigned int*)(z + (size_t)N_NODES*DIM);  // E uints
    int*   bktCnt  = (int*)(pairs + N_EDGES);              // 256
    int*   bktBase = bktCnt + 256;                         // 257 (+pad)
    int*   bktCur  = bktBase + 264;                        // 256
    float* ss      = (float*)(bktCur + 256);               // 64
    float* hg      = ss + 64;                              // 32768
    float* cwT     = hg + (size_t)NB*DIM;                  // 256000
    float* cbuf    = cwT + 256000;                         // 3964928
    float* xc      = cbuf + (size_t)NB*FCX;                // 262144
    float* y1      = xc + (size_t)NB*256;                  // 1048576
    float* y2      = y1 + (size_t)NB*1024;                 // 262144
    float* part    = y2 + (size_t)NB*256;                  // 256*64

    // ---- bucket sort of edges by dst>>8 ----
    hipMemsetAsync(bktCnt, 0, 256*sizeof(int), stream);
    k_bhist<<<N_EDGES/1024, 256, 0, stream>>>(ei, bktCnt);
    k_bscan<<<1, 256, 0, stream>>>(bktCnt, bktBase, bktCur);
    k_bucketA<<<NBKT, 256, 0, stream>>>(ei, bktCur, pairs);

    // ---- protein branch ----
    hipMemsetAsync(xc, 0, (size_t)NB*256*sizeof(float), stream);
    k_cw_transpose<<<1000, 256, 0, stream>>>(conv_w, cwT);
    k_conv<<<NB, 256, 0, stream>>>(target, emb, cwT, conv_b, cbuf);
    k_xt<<<dim3(32, 8), 256, 0, stream>>>(cbuf, w_fcxt, b_fcxt, xc);

    // ---- GIN layers ----
    for (int l=0; l<5; ++l) {
        if (l == 0)
            k_l1_transform<<<N_NODES/256, 256, 0, stream>>>(x, w1a, tH);
        else
            k_transform<<<N_NODES/256, 256, 0, stream>>>(z, ss, wa + (size_t)(l-1)*DIM*DIM, tH);
        const float* bi = (l==0) ? b1a : ba + (size_t)(l-1)*DIM;
        const float* wo = (l==0) ? w1b : wb + (size_t)(l-1)*DIM*DIM;
        const float* bo = (l==0) ? b1b : bb + (size_t)(l-1)*DIM;
        k_agg_mlp<<<NBKT, 1024, 0, stream>>>(bktBase, pairs, tH, bi, wo, bo, z, part);
        k_scaleshift<<<1, 256, 0, stream>>>(part, gamma, beta, l, ss);
    }

    // ---- pool + drug head ----
    hipMemsetAsync(hg, 0, (size_t)NB*DIM*sizeof(float), stream);
    k_pool<<<(N_NODES*32)/256, 256, 0, stream>>>(z, ss, batch, hg);
    k_xd<<<NB, 128, 0, stream>>>(hg, w_fcxd, b_fcxd, xc);

    // ---- joint head ----
    k_fc1<<<NB/4, 256, 0, stream>>>(xc, w_fc1, b_fc1, y1);
    k_fc2<<<NB/4, 256, 0, stream>>>(y1, w_fc2, b_fc2, y2);
    k_out<<<NB, 256, 0, stream>>>(y2, w_out, b_out, (float*)d_out);
}

// Round 5
// 1072.877 us; speedup vs baseline: 2.3744x; 2.3744x over previous
//
#include <hip/hip_runtime.h>
#include <hip/hip_fp16.h>

#define N_NODES 65536
#define N_EDGES 2097152
#define NB      1024
#define FXD     78
#define DIM     32
#define EMBD    128
#define OUTD    128
#define VOCAB   26
#define PLEN    1000
#define KS      8
#define CLEN    121      // EMBD-KS+1
#define NF      32
#define FCX     (NF*CLEN)  // 3872
#define NBKT    256
#define EPB     8192     // edges per bucketA block (N_EDGES/256)
#define NSLICE  256      // stats partial slices

// ---------------- bucket sort (dst>>8) ----------------

__global__ __launch_bounds__(256) void k_bhist(
    const int* __restrict__ ei, int* __restrict__ bktCnt)
{
    __shared__ int h[NBKT];
    int tid = threadIdx.x;
    h[tid] = 0;
    __syncthreads();
    int base = blockIdx.x*1024;
    #pragma unroll
    for (int q=0; q<4; ++q) {
        int d = ei[N_EDGES + base + q*256 + tid];
        atomicAdd(&h[d>>8], 1);
    }
    __syncthreads();
    atomicAdd(&bktCnt[tid], h[tid]);
}

__global__ __launch_bounds__(256) void k_bscan(
    const int* __restrict__ bktCnt, int* __restrict__ bktBase, int* __restrict__ bktCur)
{
    __shared__ int s[NBKT];
    int t = threadIdx.x;
    int v = bktCnt[t];
    s[t] = v;
    __syncthreads();
    for (int off=1; off<256; off<<=1) {
        int tv = (t >= off) ? s[t-off] : 0;
        __syncthreads();
        s[t] += tv;
        __syncthreads();
    }
    int ex = s[t] - v;
    bktBase[t] = ex;
    bktCur[t] = ex;
    if (t == 255) bktBase[256] = s[255];   // == N_EDGES
}

// LDS-sort 8192 edges by bucket, write packed (dst<<16|src) in coalesced runs
__global__ __launch_bounds__(256) void k_bucketA(
    const int* __restrict__ ei, int* __restrict__ bktCur, unsigned int* __restrict__ pairs)
{
    __shared__ unsigned int raw[EPB];       // 32 KB
    __shared__ unsigned int srt[EPB];       // 32 KB
    __shared__ unsigned char bOf[EPB];      // 8 KB
    __shared__ int hist[NBKT], sc[NBKT], lcur[NBKT], gbase[NBKT];
    int tid = threadIdx.x;
    hist[tid] = 0;
    __syncthreads();
    int eb = blockIdx.x * EPB;
    for (int i=tid; i<EPB; i+=256) {
        int s = ei[eb+i];
        int d = ei[N_EDGES+eb+i];
        raw[i] = ((unsigned int)d<<16) | (unsigned int)s;
        atomicAdd(&hist[d>>8], 1);
    }
    __syncthreads();
    int v = hist[tid];
    sc[tid] = v;
    __syncthreads();
    for (int off=1; off<256; off<<=1) {
        int tv = (tid >= off) ? sc[tid-off] : 0;
        __syncthreads();
        sc[tid] += tv;
        __syncthreads();
    }
    int ex = sc[tid] - v;
    sc[tid] = ex;            // exclusive local base
    lcur[tid] = ex;
    gbase[tid] = atomicAdd(&bktCur[tid], v);
    __syncthreads();
    for (int i=tid; i<EPB; i+=256) {
        unsigned int p = raw[i];
        int k = p >> 24;
        int pos = atomicAdd(&lcur[k], 1);
        srt[pos] = p;
        bOf[pos] = (unsigned char)k;
    }
    __syncthreads();
    for (int i=tid; i<EPB; i+=256) {
        int k = bOf[i];
        pairs[gbase[k] + (i - sc[k])] = srt[i];
    }
}

// per bucket: scatter srcs into this bucket's contiguous CSR segment.
// All stores confined to one ~32KB window owned by this block -> L2 write-merge.
__global__ __launch_bounds__(256) void k_fillB(
    const int* __restrict__ bktBase, const unsigned int* __restrict__ pairs,
    const int* __restrict__ rowptr, int* __restrict__ csr)
{
    __shared__ int cur[256];
    int b = blockIdx.x, tid = threadIdx.x;
    int node0 = b*256;
    cur[tid] = rowptr[node0 + tid];
    __syncthreads();
    int s = bktBase[b], e = bktBase[b+1];
    for (int i = s + tid; i < e; i += 256) {
        unsigned int p = pairs[i];
        int src = (int)(p & 0xFFFFu);
        int dl  = (int)(p >> 16) - node0;   // 0..255
        int pos = atomicAdd(&cur[dl], 1);
        csr[pos] = src;
    }
}

// ---------------- rowptr build ----------------

__global__ __launch_bounds__(256) void k_deg(
    const int* __restrict__ ei, int* __restrict__ deg)
{
    int e = blockIdx.x*256 + threadIdx.x;
    atomicAdd(&deg[ei[N_EDGES + e]], 1);
}

__global__ __launch_bounds__(256) void k_scan1(
    const int* __restrict__ deg, int* __restrict__ rowptr, int* __restrict__ bsum)
{
    __shared__ int s[256];
    int n = blockIdx.x*256 + threadIdx.x;
    int v = deg[n];
    s[threadIdx.x] = v;
    __syncthreads();
    for (int off=1; off<256; off<<=1) {
        int tv = (threadIdx.x >= off) ? s[threadIdx.x-off] : 0;
        __syncthreads();
        s[threadIdx.x] += tv;
        __syncthreads();
    }
    rowptr[n] = s[threadIdx.x] - v;     // exclusive
    if (threadIdx.x == 255) bsum[blockIdx.x] = s[255];
}

__global__ __launch_bounds__(256) void k_scan2(
    const int* __restrict__ bsum, int* __restrict__ boffs)
{
    __shared__ int s[256];
    int v = bsum[threadIdx.x];
    s[threadIdx.x] = v;
    __syncthreads();
    for (int off=1; off<256; off<<=1) {
        int tv = (threadIdx.x >= off) ? s[threadIdx.x-off] : 0;
        __syncthreads();
        s[threadIdx.x] += tv;
        __syncthreads();
    }
    boffs[threadIdx.x] = s[threadIdx.x] - v;  // exclusive
}

__global__ __launch_bounds__(256) void k_scan3(
    int* __restrict__ rowptr, const int* __restrict__ boffs)
{
    int n = blockIdx.x*256 + threadIdx.x;
    rowptr[n] = rowptr[n] + boffs[n >> 8];
    if (n == 0) rowptr[N_NODES] = N_EDGES;
}

// ---------------- GIN layer kernels ----------------

// Layer-1 transform: t = x @ w1a  (fp16 out)
__global__ __launch_bounds__(256) void k_l1_transform(
    const float* __restrict__ x, const float* __restrict__ w,
    __half* __restrict__ t)
{
    __shared__ float wS[FXD*DIM];
    for (int i = threadIdx.x; i < FXD*DIM; i += 256) wS[i] = w[i];
    __syncthreads();
    int node = blockIdx.x*256 + threadIdx.x;
    float acc[DIM];
    #pragma unroll
    for (int d=0; d<DIM; ++d) acc[d] = 0.f;
    const float* xr = x + (long)node*FXD;
    for (int j=0; j<FXD; ++j) {
        float xv = xr[j];
        #pragma unroll
        for (int d=0; d<DIM; ++d) acc[d] += xv * wS[j*DIM+d];
    }
    union { __half2 h2[16]; uint4 u4[4]; } pk;
    #pragma unroll
    for (int q=0; q<16; ++q) pk.h2[q] = __floats2half2_rn(acc[2*q], acc[2*q+1]);
    uint4* dst4 = (uint4*)(t + (long)node*DIM);
    #pragma unroll
    for (int q=0; q<4; ++q) dst4[q] = pk.u4[q];
}

// Layers 2-5: h = BN(z) via scale/shift; t = h @ w  (fp16 out)
__global__ __launch_bounds__(256) void k_transform(
    const float* __restrict__ z, const float* __restrict__ ss,
    const float* __restrict__ w, __half* __restrict__ t)
{
    __shared__ float wS[DIM*DIM];
    __shared__ float sS[2*DIM];
    for (int i = threadIdx.x; i < DIM*DIM; i += 256) wS[i] = w[i];
    if (threadIdx.x < 2*DIM) sS[threadIdx.x] = ss[threadIdx.x];
    __syncthreads();
    int node = blockIdx.x*256 + threadIdx.x;
    float h[DIM];
    const float4* z4 = (const float4*)(z + (long)node*DIM);
    #pragma unroll
    for (int q=0; q<DIM/4; ++q) {
        float4 v = z4[q];
        h[q*4+0]=v.x; h[q*4+1]=v.y; h[q*4+2]=v.z; h[q*4+3]=v.w;
    }
    #pragma unroll
    for (int d=0; d<DIM; ++d) h[d] = h[d]*sS[d] + sS[DIM+d];
    float acc[DIM];
    #pragma unroll
    for (int d=0; d<DIM; ++d) acc[d] = 0.f;
    #pragma unroll
    for (int j=0; j<DIM; ++j) {
        float hv = h[j];
        #pragma unroll
        for (int d=0; d<DIM; ++d) acc[d] += hv * wS[j*DIM+d];
    }
    union { __half2 h2[16]; uint4 u4[4]; } pk;
    #pragma unroll
    for (int q=0; q<16; ++q) pk.h2[q] = __floats2half2_rn(acc[2*q], acc[2*q+1]);
    uint4* dst4 = (uint4*)(t + (long)node*DIM);
    #pragma unroll
    for (int q=0; q<4; ++q) dst4[q] = pk.u4[q];
}

// Gather (CSR) + self + MLP + ReLU + BN-stats partials. 8 nodes/block, 32 lanes/node.
__global__ __launch_bounds__(256) void k_gather_mlp(
    const int* __restrict__ rowptr, const int* __restrict__ csr,
    const __half* __restrict__ t,
    const float* __restrict__ bi, const float* __restrict__ wo, const float* __restrict__ bo,
    float* __restrict__ z, float* __restrict__ part)
{
    __shared__ float wS[DIM*DIM];
    __shared__ float bS[2*DIM];
    __shared__ float stS[2*DIM];
    int tid = threadIdx.x;
    for (int i=tid; i<DIM*DIM; i+=256) wS[i]=wo[i];
    if (tid<DIM) bS[tid]=bi[tid];
    else if (tid<2*DIM) bS[tid]=bo[tid-DIM];
    if (tid<2*DIM) stS[tid]=0.f;
    __syncthreads();
    int node = blockIdx.x*8 + (tid>>5);
    int c = tid & 31;
    float acc = __half2float(t[(long)node*DIM + c]);   // self term
    int s0 = rowptr[node], s1 = rowptr[node+1];
    int e = s0;
    for (; e+8 <= s1; e+=8) {
        int i0=csr[e],   i1=csr[e+1], i2=csr[e+2], i3=csr[e+3];
        int i4=csr[e+4], i5=csr[e+5], i6=csr[e+6], i7=csr[e+7];
        float v0=__half2float(t[(long)i0*DIM+c]), v1=__half2float(t[(long)i1*DIM+c]),
              v2=__half2float(t[(long)i2*DIM+c]), v3=__half2float(t[(long)i3*DIM+c]),
              v4=__half2float(t[(long)i4*DIM+c]), v5=__half2float(t[(long)i5*DIM+c]),
              v6=__half2float(t[(long)i6*DIM+c]), v7=__half2float(t[(long)i7*DIM+c]);
        acc += ((v0+v1)+(v2+v3)) + ((v4+v5)+(v6+v7));
    }
    for (; e<s1; ++e) acc += __half2float(t[(long)csr[e]*DIM + c]);
    float u = fmaxf(acc + bS[c], 0.f);
    float zz = bS[DIM+c];
    #pragma unroll
    for (int j=0; j<DIM; ++j) {
        float uj = __shfl(u, j, 32);
        zz += uj * wS[j*DIM+c];
    }
    zz = fmaxf(zz, 0.f);
    z[(long)node*DIM + c] = zz;
    // stats: reduce the two 32-groups of each wave, then LDS, then per-slice global
    float zs = zz + __shfl_down(zz, 32, 64);
    float zq = zz*zz;
    zq = zq + __shfl_down(zq, 32, 64);
    if ((tid & 32) == 0) {
        atomicAdd(&stS[c], zs);
        atomicAdd(&stS[DIM+c], zq);
    }
    __syncthreads();
    if (tid < 2*DIM)
        atomicAdd(&part[((blockIdx.x & (NSLICE-1))<<6) + tid], stS[tid]);
}

// reduce partial stats -> scale/shift; re-zero partials for next layer
__global__ __launch_bounds__(256) void k_scaleshift(
    float* __restrict__ part,
    const float* __restrict__ gamma, const float* __restrict__ beta,
    int layer, float* __restrict__ ss)
{
    __shared__ float red[4][64];
    __shared__ float totS[64];
    int t = threadIdx.x;
    int ch = t & 63, q = t >> 6;
    float s = 0.f;
    for (int i = q*64; i < q*64 + 64; ++i) s += part[(i<<6) + ch];
    red[q][ch] = s;
    __syncthreads();
    if (t < 64) totS[t] = red[0][t]+red[1][t]+red[2][t]+red[3][t];
    __syncthreads();
    if (t < DIM) {
        float mean = totS[t] * (1.f/N_NODES);
        float var  = totS[DIM+t] * (1.f/N_NODES) - mean*mean;
        float sc = gamma[layer*DIM+t] * rsqrtf(var + 1e-5f);
        ss[t] = sc;
        ss[DIM+t] = beta[layer*DIM+t] - mean*sc;
    }
    for (int i = t; i < NSLICE*64; i += 256) part[i] = 0.f;
}

// Global add pool with BN applied: hg[batch[n]] += BN(z[n])
__global__ __launch_bounds__(256) void k_pool(
    const float* __restrict__ z, const float* __restrict__ ss,
    const int* __restrict__ batch, float* __restrict__ hg)
{
    long g = (long)blockIdx.x*256 + threadIdx.x;
    int node = (int)(g >> 5);
    int c = (int)(g & 31);
    int b = batch[node];
    float v = z[(long)node*DIM + c]*ss[c] + ss[DIM+c];
    atomicAdd(&hg[b*DIM + c], v);
}

// xd = ReLU(hg @ w_fcxd + b) -> xc[:, 0:128]
__global__ __launch_bounds__(128) void k_xd(
    const float* __restrict__ hg, const float* __restrict__ w,
    const float* __restrict__ bias, float* __restrict__ xc)
{
    int b = blockIdx.x, n = threadIdx.x;
    __shared__ float hS[DIM];
    if (n < DIM) hS[n] = hg[b*DIM+n];
    __syncthreads();
    float acc = bias[n];
    #pragma unroll
    for (int r=0; r<DIM; ++r) acc += hS[r]*w[r*OUTD+n];
    xc[b*256 + n] = fmaxf(acc, 0.f);
}

// ---------------- protein branch ----------------

__global__ __launch_bounds__(256) void k_cw_transpose(
    const float* __restrict__ cw, float* __restrict__ cwT)
{
    int g = blockIdx.x*256 + threadIdx.x;   // 256000 total
    int i = g >> 8;
    int j = g & 255;
    int o = j >> 3, k = j & 7;
    cwT[g] = cw[o*(PLEN*KS) + i*KS + k];
}

__global__ __launch_bounds__(256) void k_conv(
    const int* __restrict__ target, const float* __restrict__ emb,
    const float* __restrict__ cwT, const float* __restrict__ conv_b,
    float* __restrict__ c)
{
    __shared__ float embS[VOCAB*EMBD + 8];
    __shared__ float Gs[VOCAB*256];
    __shared__ int   sortedS[PLEN];
    __shared__ int   cntS[VOCAB];
    __shared__ int   segS[VOCAB+1];
    __shared__ int   curS[VOCAB];
    __shared__ float cbS[NF];
    int b = blockIdx.x, j = threadIdx.x;
    for (int i=j; i<VOCAB*EMBD; i+=256) embS[i] = emb[i];
    if (j < VOCAB) cntS[j] = 0;
    if (j < NF) cbS[j] = conv_b[j];
    __syncthreads();
    int tloc[4];
    #pragma unroll
    for (int q=0; q<4; ++q) {
        int i = j + q*256;
        if (i < PLEN) {
            tloc[q] = target[b*PLEN+i];
            atomicAdd(&cntS[tloc[q]], 1);
        } else tloc[q] = -1;
    }
    __syncthreads();
    if (j == 0) {
        int run = 0;
        for (int v=0; v<VOCAB; ++v) { segS[v]=run; run += cntS[v]; }
        segS[VOCAB] = run;
    }
    __syncthreads();
    if (j < VOCAB) curS[j] = segS[j];
    __syncthreads();
    #pragma unroll
    for (int q=0; q<4; ++q) {
        int i = j + q*256;
        if (i < PLEN) {
            int pos = atomicAdd(&curS[tloc[q]], 1);
            sortedS[pos] = i;
        }
    }
    __syncthreads();
    for (int v=0; v<VOCAB; ++v) {
        int s = segS[v], e2 = segS[v+1];
        float acc = 0.f;
        int p = s;
        for (; p+4 <= e2; p += 4) {
            int i0=sortedS[p], i1=sortedS[p+1], i2=sortedS[p+2], i3=sortedS[p+3];
            acc += cwT[i0*256+j] + cwT[i1*256+j] + cwT[i2*256+j] + cwT[i3*256+j];
        }
        for (; p<e2; ++p) acc += cwT[sortedS[p]*256+j];
        Gs[v*256+j] = acc;
    }
    __syncthreads();
    int o = j >> 3, pg = j & 7;
    int t0 = pg*16;
    int tcnt = (t0+16 <= CLEN) ? 16 : (CLEN - t0);   // 16 or 9
    float out[16];
    #pragma unroll
    for (int q=0; q<16; ++q) out[q] = cbS[o];
    for (int v=0; v<VOCAB; ++v) {
        float g[KS];
        #pragma unroll
        for (int k=0; k<KS; ++k) g[k] = Gs[v*256 + o*KS + k];
        float e[23];
        const float* ev = &embS[v*EMBD + t0];
        #pragma unroll
        for (int m=0; m<23; ++m) e[m] = ev[m];
        #pragma unroll
        for (int q=0; q<16; ++q) {
            float s = 0.f;
            #pragma unroll
            for (int k=0; k<KS; ++k) s += e[q+k]*g[k];
            out[q] += s;
        }
    }
    __syncthreads();
    float* stage = Gs;
    for (int q=0; q<tcnt; ++q) stage[o*CLEN + t0 + q] = out[q];
    __syncthreads();
    for (int idx=j; idx<FCX; idx+=256)
        c[(long)b*FCX + idx] = stage[idx];
}

// xt: [1024 x 3872] @ [3872 x 128] tiled GEMM with 8-way K-split.
#define XT_KSL 484
#define XT_BK  44
__global__ __launch_bounds__(256) void k_xt(
    const float* __restrict__ c, const float* __restrict__ w,
    const float* __restrict__ bias, float* __restrict__ xc)
{
    __shared__ float cS[32][XT_BK];
    __shared__ float wS[XT_BK][128];
    int b0 = blockIdx.x * 32;
    int ks0 = blockIdx.y * XT_KSL;
    int tid = threadIdx.x;
    int cg = tid >> 5;          // graph group 0..7
    int co = tid & 31;          // col group 0..31
    float acc[4][4];
    #pragma unroll
    for (int i2=0;i2<4;++i2)
      #pragma unroll
      for (int j2=0;j2<4;++j2) acc[i2][j2]=0.f;
    for (int ch=0; ch<11; ++ch) {
        int k0 = ks0 + ch*XT_BK;
        for (int idx=tid; idx<32*XT_BK; idx+=256) {
            int g = idx / XT_BK, kk = idx - g*XT_BK;
            cS[g][kk] = c[(long)(b0+g)*FCX + k0 + kk];
        }
        for (int idx=tid; idx<XT_BK*128; idx+=256) {
            int kk = idx >> 7, n = idx & 127;
            wS[kk][n] = w[(long)(k0+kk)*OUTD + n];
        }
        __syncthreads();
        #pragma unroll 4
        for (int kk=0; kk<XT_BK; ++kk) {
            float cv[4], wv[4];
            #pragma unroll
            for (int q=0;q<4;++q) cv[q] = cS[cg*4+q][kk];
            #pragma unroll
            for (int p=0;p<4;++p) wv[p] = wS[kk][co*4+p];
            #pragma unroll
            for (int q=0;q<4;++q)
              #pragma unroll
              for (int p=0;p<4;++p) acc[q][p] += cv[q]*wv[p];
        }
        __syncthreads();
    }
    #pragma unroll
    for (int q=0;q<4;++q) {
        int g = b0 + cg*4 + q;
        #pragma unroll
        for (int p=0;p<4;++p) {
            int n = co*4 + p;
            float v = acc[q][p];
            if (blockIdx.y == 0) v += bias[n];
            atomicAdd(&xc[g*256 + 128 + n], v);
        }
    }
}

// ---------------- joint head ----------------

__global__ __launch_bounds__(256) void k_fc1(
    const float* __restrict__ xc, const float* __restrict__ w,
    const float* __restrict__ bias, float* __restrict__ y)
{
    __shared__ float xS[4][256];
    int b0 = blockIdx.x*4, n = threadIdx.x;
    #pragma unroll
    for (int q=0; q<4; ++q) xS[q][n] = xc[(b0+q)*256 + n];
    __syncthreads();
    float acc[4][4];
    #pragma unroll
    for (int m=0; m<4; ++m) {
        float bv = bias[m*256+n];
        #pragma unroll
        for (int q=0; q<4; ++q) acc[q][m] = bv;
    }
    for (int r=0; r<256; ++r) {
        float x0=xS[0][r], x1=xS[1][r], x2=xS[2][r], x3=xS[3][r];
        #pragma unroll
        for (int m=0; m<4; ++m) {
            float wv = w[r*1024 + m*256 + n];
            acc[0][m]+=x0*wv; acc[1][m]+=x1*wv; acc[2][m]+=x2*wv; acc[3][m]+=x3*wv;
        }
    }
    #pragma unroll
    for (int q=0; q<4; ++q)
        #pragma unroll
        for (int m=0; m<4; ++m)
            y[(b0+q)*1024 + m*256 + n] = fmaxf(acc[q][m], 0.f);
}

__global__ __launch_bounds__(256) void k_fc2(
    const float* __restrict__ y, const float* __restrict__ w,
    const float* __restrict__ bias, float* __restrict__ y2)
{
    __shared__ float xS[4][1024];
    int b0 = blockIdx.x*4, n = threadIdx.x;
    #pragma unroll
    for (int q=0; q<4; ++q)
        for (int i=n; i<1024; i+=256) xS[q][i] = y[(b0+q)*1024 + i];
    __syncthreads();
    float acc[4];
    #pragma unroll
    for (int q=0; q<4; ++q) acc[q] = bias[n];
    for (int r=0; r<1024; ++r) {
        float wv = w[r*256 + n];
        #pragma unroll
        for (int q=0; q<4; ++q) acc[q] += xS[q][r]*wv;
    }
    #pragma unroll
    for (int q=0; q<4; ++q) y2[(b0+q)*256 + n] = fmaxf(acc[q], 0.f);
}

__global__ __launch_bounds__(256) void k_out(
    const float* __restrict__ y2, const float* __restrict__ w,
    const float* __restrict__ bias, float* __restrict__ out)
{
    int b = blockIdx.x, n = threadIdx.x;
    float v = y2[b*256 + n] * w[n];
    #pragma unroll
    for (int off=32; off; off>>=1) v += __shfl_down(v, off, 64);
    __shared__ float red[4];
    if ((n & 63) == 0) red[n >> 6] = v;
    __syncthreads();
    if (n == 0) out[b] = red[0]+red[1]+red[2]+red[3] + bias[0];
}

// ---------------- launch ----------------

extern "C" void kernel_launch(void* const* d_in, const int* in_sizes, int n_in,
                              void* d_out, int out_size, void* d_ws, size_t ws_size,
                              hipStream_t stream) {
    const float* x      = (const float*)d_in[0];
    const int*   ei     = (const int*)  d_in[1];
    const int*   batch  = (const int*)  d_in[2];
    const int*   target = (const int*)  d_in[3];
    const float* w1a    = (const float*)d_in[4];
    const float* b1a    = (const float*)d_in[5];
    const float* w1b    = (const float*)d_in[6];
    const float* b1b    = (const float*)d_in[7];
    const float* wa     = (const float*)d_in[8];
    const float* ba     = (const float*)d_in[9];
    const float* wb     = (const float*)d_in[10];
    const float* bb     = (const float*)d_in[11];
    const float* gamma  = (const float*)d_in[12];
    const float* beta   = (const float*)d_in[13];
    const float* w_fcxd = (const float*)d_in[14];
    const float* b_fcxd = (const float*)d_in[15];
    const float* emb    = (const float*)d_in[16];
    const float* conv_w = (const float*)d_in[17];
    const float* conv_b = (const float*)d_in[18];
    const float* w_fcxt = (const float*)d_in[19];
    const float* b_fcxt = (const float*)d_in[20];
    const float* w_fc1  = (const float*)d_in[21];
    const float* b_fc1  = (const float*)d_in[22];
    const float* w_fc2  = (const float*)d_in[23];
    const float* b_fc2  = (const float*)d_in[24];
    const float* w_out  = (const float*)d_in[25];
    const float* b_out  = (const float*)d_in[26];

    float* ws      = (float*)d_ws;
    __half* tH     = (__half*)ws;                          // N*32 halfs = 1,048,576 float-slots
    float* z       = ws + 1048576;                         // N*32 floats
    unsigned int* pairs = (unsigned int*)(z + (size_t)N_NODES*DIM);  // E uints
    int*   csr     = (int*)(pairs + N_EDGES);              // E ints
    int*   rowptr  = csr + N_EDGES;                        // N+1 (+pad)
    int*   deg     = rowptr + (N_NODES + 8);               // N
    int*   bsum    = deg + N_NODES;                        // 256
    int*   boffs   = bsum + 256;                           // 256
    int*   bktCnt  = boffs + 256;                          // 256
    int*   bktBase = bktCnt + 256;                         // 257 (+pad)
    int*   bktCur  = bktBase + 264;                        // 256
    float* ss      = (float*)(bktCur + 256);               // 64
    float* hg      = ss + 64;                              // 32768
    float* cwT     = hg + (size_t)NB*DIM;                  // 256000
    float* cbuf    = cwT + 256000;                         // 3964928
    float* xc      = cbuf + (size_t)NB*FCX;                // 262144
    float* y1      = xc + (size_t)NB*256;                  // 1048576
    float* y2      = y1 + (size_t)NB*1024;                 // 262144
    float* part    = y2 + (size_t)NB*256;                  // 256*64

    // ---- CSR build: bucket sort (coalesced) + per-bucket scatter ----
    hipMemsetAsync(bktCnt, 0, 256*sizeof(int), stream);
    hipMemsetAsync(deg, 0, N_NODES*sizeof(int), stream);
    k_bhist<<<N_EDGES/1024, 256, 0, stream>>>(ei, bktCnt);
    k_bscan<<<1, 256, 0, stream>>>(bktCnt, bktBase, bktCur);
    k_bucketA<<<NBKT, 256, 0, stream>>>(ei, bktCur, pairs);
    k_deg<<<N_EDGES/256, 256, 0, stream>>>(ei, deg);
    k_scan1<<<N_NODES/256, 256, 0, stream>>>(deg, rowptr, bsum);
    k_scan2<<<1, 256, 0, stream>>>(bsum, boffs);
    k_scan3<<<N_NODES/256, 256, 0, stream>>>(rowptr, boffs);
    k_fillB<<<NBKT, 256, 0, stream>>>(bktBase, pairs, rowptr, csr);

    // ---- protein branch ----
    hipMemsetAsync(xc, 0, (size_t)NB*256*sizeof(float), stream);
    k_cw_transpose<<<1000, 256, 0, stream>>>(conv_w, cwT);
    k_conv<<<NB, 256, 0, stream>>>(target, emb, cwT, conv_b, cbuf);
    k_xt<<<dim3(32, 8), 256, 0, stream>>>(cbuf, w_fcxt, b_fcxt, xc);

    // ---- GIN layers ----
    hipMemsetAsync(part, 0, NSLICE*64*sizeof(float), stream);
    for (int l=0; l<5; ++l) {
        if (l == 0)
            k_l1_transform<<<N_NODES/256, 256, 0, stream>>>(x, w1a, tH);
        else
            k_transform<<<N_NODES/256, 256, 0, stream>>>(z, ss, wa + (size_t)(l-1)*DIM*DIM, tH);
        const float* bi = (l==0) ? b1a : ba + (size_t)(l-1)*DIM;
        const float* wo = (l==0) ? w1b : wb + (size_t)(l-1)*DIM*DIM;
        const float* bo = (l==0) ? b1b : bb + (size_t)(l-1)*DIM;
        k_gather_mlp<<<N_NODES/8, 256, 0, stream>>>(rowptr, csr, tH, bi, wo, bo, z, part);
        k_scaleshift<<<1, 256, 0, stream>>>(part, gamma, beta, l, ss);
    }

    // ---- pool + drug head ----
    hipMemsetAsync(hg, 0, (size_t)NB*DIM*sizeof(float), stream);
    k_pool<<<(N_NODES*32)/256, 256, 0, stream>>>(z, ss, batch, hg);
    k_xd<<<NB, 128, 0, stream>>>(hg, w_fcxd, b_fcxd, xc);

    // ---- joint head ----
    k_fc1<<<NB/4, 256, 0, stream>>>(xc, w_fc1, b_fc1, y1);
    k_fc2<<<NB/4, 256, 0, stream>>>(y1, w_fc2, b_fc2, y2);
    k_out<<<NB, 256, 0, stream>>>(y2, w_out, b_out, (float*)d_out);
}

// Round 6
// 952.515 us; speedup vs baseline: 2.6744x; 1.1264x over previous
//
#include <hip/hip_runtime.h>
#include <hip/hip_fp16.h>

#define N_NODES 65536
#define N_EDGES 2097152
#define NB      1024
#define FXD     78
#define DIM     32
#define EMBD    128
#define OUTD    128
#define VOCAB   26
#define PLEN    1000
#define KS      8
#define CLEN    121      // EMBD-KS+1
#define NF      32
#define FCX     (NF*CLEN)  // 3872
#define NBKT    256
#define EPB     8192     // edges per bucketA block (N_EDGES/256)
#define NSLICE  256      // stats partial slices
#define EROW    136      // skewed emb row stride: f(t)=t+(t>>4), max f(127)=134

// ---------------- bucket sort (dst>>8) ----------------

__global__ __launch_bounds__(256) void k_bhist(
    const int* __restrict__ ei, int* __restrict__ bktCnt)
{
    __shared__ int h[NBKT];
    int tid = threadIdx.x;
    h[tid] = 0;
    __syncthreads();
    int base = blockIdx.x*1024;
    #pragma unroll
    for (int q=0; q<4; ++q) {
        int d = ei[N_EDGES + base + q*256 + tid];
        atomicAdd(&h[d>>8], 1);
    }
    __syncthreads();
    atomicAdd(&bktCnt[tid], h[tid]);
}

__global__ __launch_bounds__(256) void k_bscan(
    const int* __restrict__ bktCnt, int* __restrict__ bktBase, int* __restrict__ bktCur)
{
    __shared__ int s[NBKT];
    int t = threadIdx.x;
    int v = bktCnt[t];
    s[t] = v;
    __syncthreads();
    for (int off=1; off<256; off<<=1) {
        int tv = (t >= off) ? s[t-off] : 0;
        __syncthreads();
        s[t] += tv;
        __syncthreads();
    }
    int ex = s[t] - v;
    bktBase[t] = ex;
    bktCur[t] = ex;
    if (t == 255) bktBase[256] = s[255];   // == N_EDGES
}

// LDS-sort 8192 edges by bucket, write packed (dst<<16|src) in coalesced runs
__global__ __launch_bounds__(256) void k_bucketA(
    const int* __restrict__ ei, int* __restrict__ bktCur, unsigned int* __restrict__ pairs)
{
    __shared__ unsigned int raw[EPB];       // 32 KB
    __shared__ unsigned int srt[EPB];       // 32 KB
    __shared__ unsigned char bOf[EPB];      // 8 KB
    __shared__ int hist[NBKT], sc[NBKT], lcur[NBKT], gbase[NBKT];
    int tid = threadIdx.x;
    hist[tid] = 0;
    __syncthreads();
    int eb = blockIdx.x * EPB;
    for (int i=tid; i<EPB; i+=256) {
        int s = ei[eb+i];
        int d = ei[N_EDGES+eb+i];
        raw[i] = ((unsigned int)d<<16) | (unsigned int)s;
        atomicAdd(&hist[d>>8], 1);
    }
    __syncthreads();
    int v = hist[tid];
    sc[tid] = v;
    __syncthreads();
    for (int off=1; off<256; off<<=1) {
        int tv = (tid >= off) ? sc[tid-off] : 0;
        __syncthreads();
        sc[tid] += tv;
        __syncthreads();
    }
    int ex = sc[tid] - v;
    sc[tid] = ex;            // exclusive local base
    lcur[tid] = ex;
    gbase[tid] = atomicAdd(&bktCur[tid], v);
    __syncthreads();
    for (int i=tid; i<EPB; i+=256) {
        unsigned int p = raw[i];
        int k = p >> 24;
        int pos = atomicAdd(&lcur[k], 1);
        srt[pos] = p;
        bOf[pos] = (unsigned char)k;
    }
    __syncthreads();
    for (int i=tid; i<EPB; i+=256) {
        int k = bOf[i];
        pairs[gbase[k] + (i - sc[k])] = srt[i];
    }
}

// per bucket: scatter srcs into this bucket's contiguous CSR segment.
__global__ __launch_bounds__(256) void k_fillB(
    const int* __restrict__ bktBase, const unsigned int* __restrict__ pairs,
    const int* __restrict__ rowptr, int* __restrict__ csr)
{
    __shared__ int cur[256];
    int b = blockIdx.x, tid = threadIdx.x;
    int node0 = b*256;
    cur[tid] = rowptr[node0 + tid];
    __syncthreads();
    int s = bktBase[b], e = bktBase[b+1];
    for (int i = s + tid; i < e; i += 256) {
        unsigned int p = pairs[i];
        int src = (int)(p & 0xFFFFu);
        int dl  = (int)(p >> 16) - node0;   // 0..255
        int pos = atomicAdd(&cur[dl], 1);
        csr[pos] = src;
    }
}

// ---------------- rowptr build ----------------

__global__ __launch_bounds__(256) void k_deg(
    const int* __restrict__ ei, int* __restrict__ deg)
{
    int e = blockIdx.x*256 + threadIdx.x;
    atomicAdd(&deg[ei[N_EDGES + e]], 1);
}

__global__ __launch_bounds__(256) void k_scan1(
    const int* __restrict__ deg, int* __restrict__ rowptr, int* __restrict__ bsum)
{
    __shared__ int s[256];
    int n = blockIdx.x*256 + threadIdx.x;
    int v = deg[n];
    s[threadIdx.x] = v;
    __syncthreads();
    for (int off=1; off<256; off<<=1) {
        int tv = (threadIdx.x >= off) ? s[threadIdx.x-off] : 0;
        __syncthreads();
        s[threadIdx.x] += tv;
        __syncthreads();
    }
    rowptr[n] = s[threadIdx.x] - v;     // exclusive
    if (threadIdx.x == 255) bsum[blockIdx.x] = s[255];
}

__global__ __launch_bounds__(256) void k_scan2(
    const int* __restrict__ bsum, int* __restrict__ boffs)
{
    __shared__ int s[256];
    int v = bsum[threadIdx.x];
    s[threadIdx.x] = v;
    __syncthreads();
    for (int off=1; off<256; off<<=1) {
        int tv = (threadIdx.x >= off) ? s[threadIdx.x-off] : 0;
        __syncthreads();
        s[threadIdx.x] += tv;
        __syncthreads();
    }
    boffs[threadIdx.x] = s[threadIdx.x] - v;  // exclusive
}

__global__ __launch_bounds__(256) void k_scan3(
    int* __restrict__ rowptr, const int* __restrict__ boffs)
{
    int n = blockIdx.x*256 + threadIdx.x;
    rowptr[n] = rowptr[n] + boffs[n >> 8];
    if (n == 0) rowptr[N_NODES] = N_EDGES;
}

// ---------------- GIN layer kernels ----------------

// Layer-1 transform: t = x @ w1a  (fp16 out)
__global__ __launch_bounds__(256) void k_l1_transform(
    const float* __restrict__ x, const float* __restrict__ w,
    __half* __restrict__ t)
{
    __shared__ float wS[FXD*DIM];
    for (int i = threadIdx.x; i < FXD*DIM; i += 256) wS[i] = w[i];
    __syncthreads();
    int node = blockIdx.x*256 + threadIdx.x;
    float acc[DIM];
    #pragma unroll
    for (int d=0; d<DIM; ++d) acc[d] = 0.f;
    const float* xr = x + (long)node*FXD;
    for (int j=0; j<FXD; ++j) {
        float xv = xr[j];
        #pragma unroll
        for (int d=0; d<DIM; ++d) acc[d] += xv * wS[j*DIM+d];
    }
    union { __half2 h2[16]; uint4 u4[4]; } pk;
    #pragma unroll
    for (int q=0; q<16; ++q) pk.h2[q] = __floats2half2_rn(acc[2*q], acc[2*q+1]);
    uint4* dst4 = (uint4*)(t + (long)node*DIM);
    #pragma unroll
    for (int q=0; q<4; ++q) dst4[q] = pk.u4[q];
}

// Layers 2-5: h = BN(z) via scale/shift; t = h @ w  (fp16 out)
__global__ __launch_bounds__(256) void k_transform(
    const float* __restrict__ z, const float* __restrict__ ss,
    const float* __restrict__ w, __half* __restrict__ t)
{
    __shared__ float wS[DIM*DIM];
    __shared__ float sS[2*DIM];
    for (int i = threadIdx.x; i < DIM*DIM; i += 256) wS[i] = w[i];
    if (threadIdx.x < 2*DIM) sS[threadIdx.x] = ss[threadIdx.x];
    __syncthreads();
    int node = blockIdx.x*256 + threadIdx.x;
    float h[DIM];
    const float4* z4 = (const float4*)(z + (long)node*DIM);
    #pragma unroll
    for (int q=0; q<DIM/4; ++q) {
        float4 v = z4[q];
        h[q*4+0]=v.x; h[q*4+1]=v.y; h[q*4+2]=v.z; h[q*4+3]=v.w;
    }
    #pragma unroll
    for (int d=0; d<DIM; ++d) h[d] = h[d]*sS[d] + sS[DIM+d];
    float acc[DIM];
    #pragma unroll
    for (int d=0; d<DIM; ++d) acc[d] = 0.f;
    #pragma unroll
    for (int j=0; j<DIM; ++j) {
        float hv = h[j];
        #pragma unroll
        for (int d=0; d<DIM; ++d) acc[d] += hv * wS[j*DIM+d];
    }
    union { __half2 h2[16]; uint4 u4[4]; } pk;
    #pragma unroll
    for (int q=0; q<16; ++q) pk.h2[q] = __floats2half2_rn(acc[2*q], acc[2*q+1]);
    uint4* dst4 = (uint4*)(t + (long)node*DIM);
    #pragma unroll
    for (int q=0; q<4; ++q) dst4[q] = pk.u4[q];
}

// Gather (CSR) + self + MLP + ReLU + BN-stats partials.
// half2 path: 16 lanes/node (4B/lane), 16 nodes/block.
__global__ __launch_bounds__(256) void k_gather_mlp(
    const int* __restrict__ rowptr, const int* __restrict__ csr,
    const __half* __restrict__ t,
    const float* __restrict__ bi, const float* __restrict__ wo, const float* __restrict__ bo,
    float* __restrict__ z, float* __restrict__ part)
{
    __shared__ float wS[DIM*DIM];
    __shared__ float bS[2*DIM];
    __shared__ float stS[2*DIM];
    int tid = threadIdx.x;
    for (int i=tid; i<DIM*DIM; i+=256) wS[i]=wo[i];
    if (tid<DIM) bS[tid]=bi[tid];
    else if (tid<2*DIM) bS[tid]=bo[tid-DIM];
    if (tid<2*DIM) stS[tid]=0.f;
    __syncthreads();
    int g  = tid >> 4;          // node group 0..15
    int c2 = tid & 15;          // half2 channel pair
    int node = blockIdx.x*16 + g;
    const __half2* t2 = (const __half2*)t;
    float2 f = __half22float2(t2[(long)node*16 + c2]);   // self term
    float ax = f.x, ay = f.y;
    int s0 = rowptr[node], s1 = rowptr[node+1];
    int e = s0;
    for (; e+8 <= s1; e+=8) {
        int i0=csr[e],   i1=csr[e+1], i2=csr[e+2], i3=csr[e+3];
        int i4=csr[e+4], i5=csr[e+5], i6=csr[e+6], i7=csr[e+7];
        float2 f0=__half22float2(t2[(long)i0*16+c2]), f1=__half22float2(t2[(long)i1*16+c2]),
               f2=__half22float2(t2[(long)i2*16+c2]), f3=__half22float2(t2[(long)i3*16+c2]),
               f4=__half22float2(t2[(long)i4*16+c2]), f5=__half22float2(t2[(long)i5*16+c2]),
               f6=__half22float2(t2[(long)i6*16+c2]), f7=__half22float2(t2[(long)i7*16+c2]);
        ax += ((f0.x+f1.x)+(f2.x+f3.x)) + ((f4.x+f5.x)+(f6.x+f7.x));
        ay += ((f0.y+f1.y)+(f2.y+f3.y)) + ((f4.y+f5.y)+(f6.y+f7.y));
    }
    for (; e<s1; ++e) {
        float2 fv = __half22float2(t2[(long)csr[e]*16 + c2]);
        ax += fv.x; ay += fv.y;
    }
    float ux = fmaxf(ax + bS[2*c2],   0.f);
    float uy = fmaxf(ay + bS[2*c2+1], 0.f);
    float zx = bS[DIM+2*c2], zy = bS[DIM+2*c2+1];
    const float2* w2 = (const float2*)wS;
    #pragma unroll
    for (int j=0; j<DIM; ++j) {
        float uj = (j & 1) ? __shfl(uy, j>>1, 16) : __shfl(ux, j>>1, 16);
        float2 wv = w2[j*16 + c2];
        zx += uj*wv.x; zy += uj*wv.y;
    }
    zx = fmaxf(zx, 0.f); zy = fmaxf(zy, 0.f);
    ((float2*)z)[(long)node*16 + c2] = make_float2(zx, zy);
    // stats: reduce the wave's 4 node-groups, then LDS, then per-slice global
    float sx = zx, sy = zy, qx = zx*zx, qy = zy*zy;
    sx += __shfl_down(sx, 32, 64); sy += __shfl_down(sy, 32, 64);
    qx += __shfl_down(qx, 32, 64); qy += __shfl_down(qy, 32, 64);
    sx += __shfl_down(sx, 16, 64); sy += __shfl_down(sy, 16, 64);
    qx += __shfl_down(qx, 16, 64); qy += __shfl_down(qy, 16, 64);
    if ((tid & 63) < 16) {
        atomicAdd(&stS[2*c2],       sx);
        atomicAdd(&stS[2*c2+1],     sy);
        atomicAdd(&stS[DIM+2*c2],   qx);
        atomicAdd(&stS[DIM+2*c2+1], qy);
    }
    __syncthreads();
    if (tid < 2*DIM)
        atomicAdd(&part[((blockIdx.x & (NSLICE-1))<<6) + tid], stS[tid]);
}

// reduce partial stats -> scale/shift; re-zero partials for next layer
__global__ __launch_bounds__(256) void k_scaleshift(
    float* __restrict__ part,
    const float* __restrict__ gamma, const float* __restrict__ beta,
    int layer, float* __restrict__ ss)
{
    __shared__ float red[4][64];
    __shared__ float totS[64];
    int t = threadIdx.x;
    int ch = t & 63, q = t >> 6;
    float s = 0.f;
    for (int i = q*64; i < q*64 + 64; ++i) s += part[(i<<6) + ch];
    red[q][ch] = s;
    __syncthreads();
    if (t < 64) totS[t] = red[0][t]+red[1][t]+red[2][t]+red[3][t];
    __syncthreads();
    if (t < DIM) {
        float mean = totS[t] * (1.f/N_NODES);
        float var  = totS[DIM+t] * (1.f/N_NODES) - mean*mean;
        float sc = gamma[layer*DIM+t] * rsqrtf(var + 1e-5f);
        ss[t] = sc;
        ss[DIM+t] = beta[layer*DIM+t] - mean*sc;
    }
    for (int i = t; i < NSLICE*64; i += 256) part[i] = 0.f;
}

// Global add pool with BN applied: hg[batch[n]] += BN(z[n])
__global__ __launch_bounds__(256) void k_pool(
    const float* __restrict__ z, const float* __restrict__ ss,
    const int* __restrict__ batch, float* __restrict__ hg)
{
    long g = (long)blockIdx.x*256 + threadIdx.x;
    int node = (int)(g >> 5);
    int c = (int)(g & 31);
    int b = batch[node];
    float v = z[(long)node*DIM + c]*ss[c] + ss[DIM+c];
    atomicAdd(&hg[b*DIM + c], v);
}

// xd = ReLU(hg @ w_fcxd + b) -> xc[:, 0:128]
__global__ __launch_bounds__(128) void k_xd(
    const float* __restrict__ hg, const float* __restrict__ w,
    const float* __restrict__ bias, float* __restrict__ xc)
{
    int b = blockIdx.x, n = threadIdx.x;
    __shared__ float hS[DIM];
    if (n < DIM) hS[n] = hg[b*DIM+n];
    __syncthreads();
    float acc = bias[n];
    #pragma unroll
    for (int r=0; r<DIM; ++r) acc += hS[r]*w[r*OUTD+n];
    xc[b*256 + n] = fmaxf(acc, 0.f);
}

// ---------------- protein branch ----------------

__global__ __launch_bounds__(256) void k_cw_transpose(
    const float* __restrict__ cw, float* __restrict__ cwT)
{
    int g = blockIdx.x*256 + threadIdx.x;   // 256000 total
    int i = g >> 8;
    int j = g & 255;
    int o = j >> 3, k = j & 7;
    cwT[g] = cw[o*(PLEN*KS) + i*KS + k];
}

__global__ __launch_bounds__(256) void k_conv(
    const int* __restrict__ target, const float* __restrict__ emb,
    const float* __restrict__ cwT, const float* __restrict__ conv_b,
    float* __restrict__ c)
{
    __shared__ float embS[VOCAB*EROW + 16];  // skewed f(t)=t+(t>>4)
    __shared__ float Gs[VOCAB*256];
    __shared__ int   sortedS[PLEN];
    __shared__ int   cntS[VOCAB];
    __shared__ int   segS[VOCAB+1];
    __shared__ int   curS[VOCAB];
    __shared__ float cbS[NF];
    int b = blockIdx.x, j = threadIdx.x;
    for (int i=j; i<VOCAB*EMBD; i+=256) {
        int v = i >> 7, tt = i & 127;
        embS[v*EROW + tt + (tt>>4)] = emb[i];
    }
    if (j < VOCAB) cntS[j] = 0;
    if (j < NF) cbS[j] = conv_b[j];
    __syncthreads();
    int tloc[4];
    #pragma unroll
    for (int q=0; q<4; ++q) {
        int i = j + q*256;
        if (i < PLEN) {
            tloc[q] = target[b*PLEN+i];
            atomicAdd(&cntS[tloc[q]], 1);
        } else tloc[q] = -1;
    }
    __syncthreads();
    if (j == 0) {
        int run = 0;
        for (int v=0; v<VOCAB; ++v) { segS[v]=run; run += cntS[v]; }
        segS[VOCAB] = run;
    }
    __syncthreads();
    if (j < VOCAB) curS[j] = segS[j];
    __syncthreads();
    #pragma unroll
    for (int q=0; q<4; ++q) {
        int i = j + q*256;
        if (i < PLEN) {
            int pos = atomicAdd(&curS[tloc[q]], 1);
            sortedS[pos] = i;
        }
    }
    __syncthreads();
    // bucket-accumulate: 8-unroll, 2 independent accumulators
    for (int v=0; v<VOCAB; ++v) {
        int s = segS[v], e2 = segS[v+1];
        float accA = 0.f, accB = 0.f;
        int p = s;
        for (; p+8 <= e2; p += 8) {
            int i0=sortedS[p],   i1=sortedS[p+1], i2=sortedS[p+2], i3=sortedS[p+3];
            int i4=sortedS[p+4], i5=sortedS[p+5], i6=sortedS[p+6], i7=sortedS[p+7];
            accA += (cwT[i0*256+j]+cwT[i1*256+j])+(cwT[i2*256+j]+cwT[i3*256+j]);
            accB += (cwT[i4*256+j]+cwT[i5*256+j])+(cwT[i6*256+j]+cwT[i7*256+j]);
        }
        for (; p<e2; ++p) accA += cwT[sortedS[p]*256+j];
        Gs[v*256+j] = accA + accB;
    }
    __syncthreads();
    int o = j >> 3, pg = j & 7;
    int t0 = pg*16;
    int tcnt = (t0+16 <= CLEN) ? 16 : (CLEN - t0);   // 16 or 9
    float out[16];
    #pragma unroll
    for (int q=0; q<16; ++q) out[q] = cbS[o];
    for (int v=0; v<VOCAB; ++v) {
        float g[KS];
        #pragma unroll
        for (int k=0; k<KS; ++k) g[k] = Gs[v*256 + o*KS + k];
        float e[23];
        const float* ev = &embS[v*EROW + 17*pg];
        #pragma unroll
        for (int m=0; m<23; ++m) e[m] = ev[m + (m>>4)];
        #pragma unroll
        for (int q=0; q<16; ++q) {
            float s = 0.f;
            #pragma unroll
            for (int k=0; k<KS; ++k) s += e[q+k]*g[k];
            out[q] += s;
        }
    }
    __syncthreads();
    float* stage = Gs;
    for (int q=0; q<tcnt; ++q) stage[o*CLEN + t0 + q] = out[q];
    __syncthreads();
    for (int idx=j; idx<FCX; idx+=256)
        c[(long)b*FCX + idx] = stage[idx];
}

// xt: [1024 x 3872] @ [3872 x 128] tiled GEMM with 8-way K-split.
#define XT_KSL 484
#define XT_BK  44
__global__ __launch_bounds__(256) void k_xt(
    const float* __restrict__ c, const float* __restrict__ w,
    const float* __restrict__ bias, float* __restrict__ xc)
{
    __shared__ float cS[32][XT_BK];
    __shared__ float wS[XT_BK][128];
    int b0 = blockIdx.x * 32;
    int ks0 = blockIdx.y * XT_KSL;
    int tid = threadIdx.x;
    int cg = tid >> 5;          // graph group 0..7
    int co = tid & 31;          // col group 0..31
    float acc[4][4];
    #pragma unroll
    for (int i2=0;i2<4;++i2)
      #pragma unroll
      for (int j2=0;j2<4;++j2) acc[i2][j2]=0.f;
    for (int ch=0; ch<11; ++ch) {
        int k0 = ks0 + ch*XT_BK;
        for (int idx=tid; idx<32*XT_BK; idx+=256) {
            int g = idx / XT_BK, kk = idx - g*XT_BK;
            cS[g][kk] = c[(long)(b0+g)*FCX + k0 + kk];
        }
        for (int idx=tid; idx<XT_BK*128; idx+=256) {
            int kk = idx >> 7, n = idx & 127;
            wS[kk][n] = w[(long)(k0+kk)*OUTD + n];
        }
        __syncthreads();
        #pragma unroll 4
        for (int kk=0; kk<XT_BK; ++kk) {
            float cv[4], wv[4];
            #pragma unroll
            for (int q=0;q<4;++q) cv[q] = cS[cg*4+q][kk];
            #pragma unroll
            for (int p=0;p<4;++p) wv[p] = wS[kk][co*4+p];
            #pragma unroll
            for (int q=0;q<4;++q)
              #pragma unroll
              for (int p=0;p<4;++p) acc[q][p] += cv[q]*wv[p];
        }
        __syncthreads();
    }
    #pragma unroll
    for (int q=0;q<4;++q) {
        int g = b0 + cg*4 + q;
        #pragma unroll
        for (int p=0;p<4;++p) {
            int n = co*4 + p;
            float v = acc[q][p];
            if (blockIdx.y == 0) v += bias[n];
            atomicAdd(&xc[g*256 + 128 + n], v);
        }
    }
}

// ---------------- joint head ----------------

__global__ __launch_bounds__(256) void k_fc1(
    const float* __restrict__ xc, const float* __restrict__ w,
    const float* __restrict__ bias, float* __restrict__ y)
{
    __shared__ float xS[4][256];
    int b0 = blockIdx.x*4, n = threadIdx.x;
    #pragma unroll
    for (int q=0; q<4; ++q) xS[q][n] = xc[(b0+q)*256 + n];
    __syncthreads();
    float acc[4][4];
    #pragma unroll
    for (int m=0; m<4; ++m) {
        float bv = bias[m*256+n];
        #pragma unroll
        for (int q=0; q<4; ++q) acc[q][m] = bv;
    }
    for (int r=0; r<256; ++r) {
        float x0=xS[0][r], x1=xS[1][r], x2=xS[2][r], x3=xS[3][r];
        #pragma unroll
        for (int m=0; m<4; ++m) {
            float wv = w[r*1024 + m*256 + n];
            acc[0][m]+=x0*wv; acc[1][m]+=x1*wv; acc[2][m]+=x2*wv; acc[3][m]+=x3*wv;
        }
    }
    #pragma unroll
    for (int q=0; q<4; ++q)
        #pragma unroll
        for (int m=0; m<4; ++m)
            y[(b0+q)*1024 + m*256 + n] = fmaxf(acc[q][m], 0.f);
}

__global__ __launch_bounds__(256) void k_fc2(
    const float* __restrict__ y, const float* __restrict__ w,
    const float* __restrict__ bias, float* __restrict__ y2)
{
    __shared__ float xS[4][1024];
    int b0 = blockIdx.x*4, n = threadIdx.x;
    #pragma unroll
    for (int q=0; q<4; ++q)
        for (int i=n; i<1024; i+=256) xS[q][i] = y[(b0+q)*1024 + i];
    __syncthreads();
    float acc[4];
    #pragma unroll
    for (int q=0; q<4; ++q) acc[q] = bias[n];
    for (int r=0; r<1024; ++r) {
        float wv = w[r*256 + n];
        #pragma unroll
        for (int q=0; q<4; ++q) acc[q] += xS[q][r]*wv;
    }
    #pragma unroll
    for (int q=0; q<4; ++q) y2[(b0+q)*256 + n] = fmaxf(acc[q], 0.f);
}

__global__ __launch_bounds__(256) void k_out(
    const float* __restrict__ y2, const float* __restrict__ w,
    const float* __restrict__ bias, float* __restrict__ out)
{
    int b = blockIdx.x, n = threadIdx.x;
    float v = y2[b*256 + n] * w[n];
    #pragma unroll
    for (int off=32; off; off>>=1) v += __shfl_down(v, off, 64);
    __shared__ float red[4];
    if ((n & 63) == 0) red[n >> 6] = v;
    __syncthreads();
    if (n == 0) out[b] = red[0]+red[1]+red[2]+red[3] + bias[0];
}

// ---------------- launch ----------------

extern "C" void kernel_launch(void* const* d_in, const int* in_sizes, int n_in,
                              void* d_out, int out_size, void* d_ws, size_t ws_size,
                              hipStream_t stream) {
    const float* x      = (const float*)d_in[0];
    const int*   ei     = (const int*)  d_in[1];
    const int*   batch  = (const int*)  d_in[2];
    const int*   target = (const int*)  d_in[3];
    const float* w1a    = (const float*)d_in[4];
    const float* b1a    = (const float*)d_in[5];
    const float* w1b    = (const float*)d_in[6];
    const float* b1b    = (const float*)d_in[7];
    const float* wa     = (const float*)d_in[8];
    const float* ba     = (const float*)d_in[9];
    const float* wb     = (const float*)d_in[10];
    const float* bb     = (const float*)d_in[11];
    const float* gamma  = (const float*)d_in[12];
    const float* beta   = (const float*)d_in[13];
    const float* w_fcxd = (const float*)d_in[14];
    const float* b_fcxd = (const float*)d_in[15];
    const float* emb    = (const float*)d_in[16];
    const float* conv_w = (const float*)d_in[17];
    const float* conv_b = (const float*)d_in[18];
    const float* w_fcxt = (const float*)d_in[19];
    const float* b_fcxt = (const float*)d_in[20];
    const float* w_fc1  = (const float*)d_in[21];
    const float* b_fc1  = (const float*)d_in[22];
    const float* w_fc2  = (const float*)d_in[23];
    const float* b_fc2  = (const float*)d_in[24];
    const float* w_out  = (const float*)d_in[25];
    const float* b_out  = (const float*)d_in[26];

    float* ws      = (float*)d_ws;
    __half* tH     = (__half*)ws;                          // N*32 halfs = 1,048,576 float-slots
    float* z       = ws + 1048576;                         // N*32 floats
    unsigned int* pairs = (unsigned int*)(z + (size_t)N_NODES*DIM);  // E uints
    int*   csr     = (int*)(pairs + N_EDGES);              // E ints
    int*   rowptr  = csr + N_EDGES;                        // N+1 (+pad)
    int*   deg     = rowptr + (N_NODES + 8);               // N
    int*   bsum    = deg + N_NODES;                        // 256
    int*   boffs   = bsum + 256;                           // 256
    int*   bktCnt  = boffs + 256;                          // 256
    int*   bktBase = bktCnt + 256;                         // 257 (+pad)
    int*   bktCur  = bktBase + 264;                        // 256
    float* ss      = (float*)(bktCur + 256);               // 64
    float* hg      = ss + 64;                              // 32768
    float* cwT     = hg + (size_t)NB*DIM;                  // 256000
    float* cbuf    = cwT + 256000;                         // 3964928
    float* xc      = cbuf + (size_t)NB*FCX;                // 262144
    float* y1      = xc + (size_t)NB*256;                  // 1048576
    float* y2      = y1 + (size_t)NB*1024;                 // 262144
    float* part    = y2 + (size_t)NB*256;                  // 256*64

    // ---- CSR build: bucket sort (coalesced) + per-bucket scatter ----
    hipMemsetAsync(bktCnt, 0, 256*sizeof(int), stream);
    hipMemsetAsync(deg, 0, N_NODES*sizeof(int), stream);
    k_bhist<<<N_EDGES/1024, 256, 0, stream>>>(ei, bktCnt);
    k_bscan<<<1, 256, 0, stream>>>(bktCnt, bktBase, bktCur);
    k_bucketA<<<NBKT, 256, 0, stream>>>(ei, bktCur, pairs);
    k_deg<<<N_EDGES/256, 256, 0, stream>>>(ei, deg);
    k_scan1<<<N_NODES/256, 256, 0, stream>>>(deg, rowptr, bsum);
    k_scan2<<<1, 256, 0, stream>>>(bsum, boffs);
    k_scan3<<<N_NODES/256, 256, 0, stream>>>(rowptr, boffs);
    k_fillB<<<NBKT, 256, 0, stream>>>(bktBase, pairs, rowptr, csr);

    // ---- protein branch ----
    hipMemsetAsync(xc, 0, (size_t)NB*256*sizeof(float), stream);
    k_cw_transpose<<<1000, 256, 0, stream>>>(conv_w, cwT);
    k_conv<<<NB, 256, 0, stream>>>(target, emb, cwT, conv_b, cbuf);
    k_xt<<<dim3(32, 8), 256, 0, stream>>>(cbuf, w_fcxt, b_fcxt, xc);

    // ---- GIN layers ----
    hipMemsetAsync(part, 0, NSLICE*64*sizeof(float), stream);
    for (int l=0; l<5; ++l) {
        if (l == 0)
            k_l1_transform<<<N_NODES/256, 256, 0, stream>>>(x, w1a, tH);
        else
            k_transform<<<N_NODES/256, 256, 0, stream>>>(z, ss, wa + (size_t)(l-1)*DIM*DIM, tH);
        const float* bi = (l==0) ? b1a : ba + (size_t)(l-1)*DIM;
        const float* wo = (l==0) ? w1b : wb + (size_t)(l-1)*DIM*DIM;
        const float* bo = (l==0) ? b1b : bb + (size_t)(l-1)*DIM;
        k_gather_mlp<<<N_NODES/16, 256, 0, stream>>>(rowptr, csr, tH, bi, wo, bo, z, part);
        k_scaleshift<<<1, 256, 0, stream>>>(part, gamma, beta, l, ss);
    }

    // ---- pool + drug head ----
    hipMemsetAsync(hg, 0, (size_t)NB*DIM*sizeof(float), stream);
    k_pool<<<(N_NODES*32)/256, 256, 0, stream>>>(z, ss, batch, hg);
    k_xd<<<NB, 128, 0, stream>>>(hg, w_fcxd, b_fcxd, xc);

    // ---- joint head ----
    k_fc1<<<NB/4, 256, 0, stream>>>(xc, w_fc1, b_fc1, y1);
    k_fc2<<<NB/4, 256, 0, stream>>>(y1, w_fc2, b_fc2, y2);
    k_out<<<NB, 256, 0, stream>>>(y2, w_out, b_out, (float*)d_out);
}

// Round 7
// 934.942 us; speedup vs baseline: 2.7247x; 1.0188x over previous
//
#include <hip/hip_runtime.h>
#include <hip/hip_fp16.h>

#define N_NODES 65536
#define N_EDGES 2097152
#define NB      1024
#define FXD     78
#define DIM     32
#define EMBD    128
#define OUTD    128
#define VOCAB   26
#define PLEN    1000
#define KS      8
#define CLEN    121      // EMBD-KS+1
#define NF      32
#define FCX     (NF*CLEN)  // 3872
#define NBKT    256
#define EPB     8192     // edges per bucketA block (N_EDGES/256)
#define NSLICE  256      // stats partial slices
#define EROW    135      // skewed emb row stride: f(t)=t+(t>>4), max f(127)=134
#define UNIF    3518     // union region floats: max(sort scratch 1079 ints, embS 26*135+8)

// ---------------- bucket sort (dst>>8) ----------------

__global__ __launch_bounds__(256) void k_bhist(
    const int* __restrict__ ei, int* __restrict__ bktCnt)
{
    __shared__ int h[NBKT];
    int tid = threadIdx.x;
    h[tid] = 0;
    __syncthreads();
    int base = blockIdx.x*1024;
    #pragma unroll
    for (int q=0; q<4; ++q) {
        int d = ei[N_EDGES + base + q*256 + tid];
        atomicAdd(&h[d>>8], 1);
    }
    __syncthreads();
    atomicAdd(&bktCnt[tid], h[tid]);
}

__global__ __launch_bounds__(256) void k_bscan(
    const int* __restrict__ bktCnt, int* __restrict__ bktBase, int* __restrict__ bktCur)
{
    __shared__ int s[NBKT];
    int t = threadIdx.x;
    int v = bktCnt[t];
    s[t] = v;
    __syncthreads();
    for (int off=1; off<256; off<<=1) {
        int tv = (t >= off) ? s[t-off] : 0;
        __syncthreads();
        s[t] += tv;
        __syncthreads();
    }
    int ex = s[t] - v;
    bktBase[t] = ex;
    bktCur[t] = ex;
    if (t == 255) bktBase[256] = s[255];   // == N_EDGES
}

// LDS-sort 8192 edges by bucket, write packed (dst<<16|src) in coalesced runs
__global__ __launch_bounds__(256) void k_bucketA(
    const int* __restrict__ ei, int* __restrict__ bktCur, unsigned int* __restrict__ pairs)
{
    __shared__ unsigned int raw[EPB];       // 32 KB
    __shared__ unsigned int srt[EPB];       // 32 KB
    __shared__ unsigned char bOf[EPB];      // 8 KB
    __shared__ int hist[NBKT], sc[NBKT], lcur[NBKT], gbase[NBKT];
    int tid = threadIdx.x;
    hist[tid] = 0;
    __syncthreads();
    int eb = blockIdx.x * EPB;
    for (int i=tid; i<EPB; i+=256) {
        int s = ei[eb+i];
        int d = ei[N_EDGES+eb+i];
        raw[i] = ((unsigned int)d<<16) | (unsigned int)s;
        atomicAdd(&hist[d>>8], 1);
    }
    __syncthreads();
    int v = hist[tid];
    sc[tid] = v;
    __syncthreads();
    for (int off=1; off<256; off<<=1) {
        int tv = (tid >= off) ? sc[tid-off] : 0;
        __syncthreads();
        sc[tid] += tv;
        __syncthreads();
    }
    int ex = sc[tid] - v;
    sc[tid] = ex;            // exclusive local base
    lcur[tid] = ex;
    gbase[tid] = atomicAdd(&bktCur[tid], v);
    __syncthreads();
    for (int i=tid; i<EPB; i+=256) {
        unsigned int p = raw[i];
        int k = p >> 24;
        int pos = atomicAdd(&lcur[k], 1);
        srt[pos] = p;
        bOf[pos] = (unsigned char)k;
    }
    __syncthreads();
    for (int i=tid; i<EPB; i+=256) {
        int k = bOf[i];
        pairs[gbase[k] + (i - sc[k])] = srt[i];
    }
}

// per bucket: scatter srcs into this bucket's contiguous CSR segment.
__global__ __launch_bounds__(256) void k_fillB(
    const int* __restrict__ bktBase, const unsigned int* __restrict__ pairs,
    const int* __restrict__ rowptr, int* __restrict__ csr)
{
    __shared__ int cur[256];
    int b = blockIdx.x, tid = threadIdx.x;
    int node0 = b*256;
    cur[tid] = rowptr[node0 + tid];
    __syncthreads();
    int s = bktBase[b], e = bktBase[b+1];
    for (int i = s + tid; i < e; i += 256) {
        unsigned int p = pairs[i];
        int src = (int)(p & 0xFFFFu);
        int dl  = (int)(p >> 16) - node0;   // 0..255
        int pos = atomicAdd(&cur[dl], 1);
        csr[pos] = src;
    }
}

// ---------------- rowptr build ----------------

__global__ __launch_bounds__(256) void k_deg(
    const int* __restrict__ ei, int* __restrict__ deg)
{
    int e = blockIdx.x*256 + threadIdx.x;
    atomicAdd(&deg[ei[N_EDGES + e]], 1);
}

__global__ __launch_bounds__(256) void k_scan1(
    const int* __restrict__ deg, int* __restrict__ rowptr, int* __restrict__ bsum)
{
    __shared__ int s[256];
    int n = blockIdx.x*256 + threadIdx.x;
    int v = deg[n];
    s[threadIdx.x] = v;
    __syncthreads();
    for (int off=1; off<256; off<<=1) {
        int tv = (threadIdx.x >= off) ? s[threadIdx.x-off] : 0;
        __syncthreads();
        s[threadIdx.x] += tv;
        __syncthreads();
    }
    rowptr[n] = s[threadIdx.x] - v;     // exclusive
    if (threadIdx.x == 255) bsum[blockIdx.x] = s[255];
}

__global__ __launch_bounds__(256) void k_scan2(
    const int* __restrict__ bsum, int* __restrict__ boffs)
{
    __shared__ int s[256];
    int v = bsum[threadIdx.x];
    s[threadIdx.x] = v;
    __syncthreads();
    for (int off=1; off<256; off<<=1) {
        int tv = (threadIdx.x >= off) ? s[threadIdx.x-off] : 0;
        __syncthreads();
        s[threadIdx.x] += tv;
        __syncthreads();
    }
    boffs[threadIdx.x] = s[threadIdx.x] - v;  // exclusive
}

__global__ __launch_bounds__(256) void k_scan3(
    int* __restrict__ rowptr, const int* __restrict__ boffs)
{
    int n = blockIdx.x*256 + threadIdx.x;
    rowptr[n] = rowptr[n] + boffs[n >> 8];
    if (n == 0) rowptr[N_NODES] = N_EDGES;
}

// ---------------- GIN layer kernels ----------------

// Layer-1 transform: t = x @ w1a  (fp16 out)
__global__ __launch_bounds__(256) void k_l1_transform(
    const float* __restrict__ x, const float* __restrict__ w,
    __half* __restrict__ t)
{
    __shared__ float wS[FXD*DIM];
    for (int i = threadIdx.x; i < FXD*DIM; i += 256) wS[i] = w[i];
    __syncthreads();
    int node = blockIdx.x*256 + threadIdx.x;
    float acc[DIM];
    #pragma unroll
    for (int d=0; d<DIM; ++d) acc[d] = 0.f;
    const float* xr = x + (long)node*FXD;
    for (int j=0; j<FXD; ++j) {
        float xv = xr[j];
        #pragma unroll
        for (int d=0; d<DIM; ++d) acc[d] += xv * wS[j*DIM+d];
    }
    union { __half2 h2[16]; uint4 u4[4]; } pk;
    #pragma unroll
    for (int q=0; q<16; ++q) pk.h2[q] = __floats2half2_rn(acc[2*q], acc[2*q+1]);
    uint4* dst4 = (uint4*)(t + (long)node*DIM);
    #pragma unroll
    for (int q=0; q<4; ++q) dst4[q] = pk.u4[q];
}

// Layers 2-5: h = BN(z) via scale/shift; t = h @ w  (fp16 out)
__global__ __launch_bounds__(256) void k_transform(
    const float* __restrict__ z, const float* __restrict__ ss,
    const float* __restrict__ w, __half* __restrict__ t)
{
    __shared__ float wS[DIM*DIM];
    __shared__ float sS[2*DIM];
    for (int i = threadIdx.x; i < DIM*DIM; i += 256) wS[i] = w[i];
    if (threadIdx.x < 2*DIM) sS[threadIdx.x] = ss[threadIdx.x];
    __syncthreads();
    int node = blockIdx.x*256 + threadIdx.x;
    float h[DIM];
    const float4* z4 = (const float4*)(z + (long)node*DIM);
    #pragma unroll
    for (int q=0; q<DIM/4; ++q) {
        float4 v = z4[q];
        h[q*4+0]=v.x; h[q*4+1]=v.y; h[q*4+2]=v.z; h[q*4+3]=v.w;
    }
    #pragma unroll
    for (int d=0; d<DIM; ++d) h[d] = h[d]*sS[d] + sS[DIM+d];
    float acc[DIM];
    #pragma unroll
    for (int d=0; d<DIM; ++d) acc[d] = 0.f;
    #pragma unroll
    for (int j=0; j<DIM; ++j) {
        float hv = h[j];
        #pragma unroll
        for (int d=0; d<DIM; ++d) acc[d] += hv * wS[j*DIM+d];
    }
    union { __half2 h2[16]; uint4 u4[4]; } pk;
    #pragma unroll
    for (int q=0; q<16; ++q) pk.h2[q] = __floats2half2_rn(acc[2*q], acc[2*q+1]);
    uint4* dst4 = (uint4*)(t + (long)node*DIM);
    #pragma unroll
    for (int q=0; q<4; ++q) dst4[q] = pk.u4[q];
}

// Gather (CSR) + self + MLP + ReLU + BN-stats partials.
// half2 path: 16 lanes/node (4B/lane), 16 nodes/block.
// csr indices: one coalesced 8-lane load + shfl broadcast (9 VMEM issues / 8 edges).
__global__ __launch_bounds__(256) void k_gather_mlp(
    const int* __restrict__ rowptr, const int* __restrict__ csr,
    const __half* __restrict__ t,
    const float* __restrict__ bi, const float* __restrict__ wo, const float* __restrict__ bo,
    float* __restrict__ z, float* __restrict__ part)
{
    __shared__ float wS[DIM*DIM];
    __shared__ float bS[2*DIM];
    __shared__ float stS[2*DIM];
    int tid = threadIdx.x;
    for (int i=tid; i<DIM*DIM; i+=256) wS[i]=wo[i];
    if (tid<DIM) bS[tid]=bi[tid];
    else if (tid<2*DIM) bS[tid]=bo[tid-DIM];
    if (tid<2*DIM) stS[tid]=0.f;
    __syncthreads();
    int g  = tid >> 4;          // node group 0..15
    int c2 = tid & 15;          // half2 channel pair
    int node = blockIdx.x*16 + g;
    const __half2* t2 = (const __half2*)t;
    float2 f = __half22float2(t2[(long)node*16 + c2]);   // self term
    float ax0 = f.x, ay0 = f.y, ax1 = 0.f, ay1 = 0.f;
    int s0 = rowptr[node], s1 = rowptr[node+1];
    int e = s0;
    for (; e+8 <= s1; e+=8) {
        int myIdx = csr[e + (c2 & 7)];      // 8 distinct addrs per group, coalesced
        #pragma unroll
        for (int k=0; k<8; ++k) {
            int idx = __shfl(myIdx, k, 8);  // broadcast csr[e+k] to all 16 lanes
            float2 fv = __half22float2(t2[(long)idx*16 + c2]);
            if (k & 1) { ax1 += fv.x; ay1 += fv.y; }
            else       { ax0 += fv.x; ay0 += fv.y; }
        }
    }
    for (; e<s1; ++e) {
        float2 fv = __half22float2(t2[(long)csr[e]*16 + c2]);
        ax0 += fv.x; ay0 += fv.y;
    }
    float ax = ax0 + ax1, ay = ay0 + ay1;
    float ux = fmaxf(ax + bS[2*c2],   0.f);
    float uy = fmaxf(ay + bS[2*c2+1], 0.f);
    float zx = bS[DIM+2*c2], zy = bS[DIM+2*c2+1];
    const float2* w2 = (const float2*)wS;
    #pragma unroll
    for (int j=0; j<DIM; ++j) {
        float uj = (j & 1) ? __shfl(uy, j>>1, 16) : __shfl(ux, j>>1, 16);
        float2 wv = w2[j*16 + c2];
        zx += uj*wv.x; zy += uj*wv.y;
    }
    zx = fmaxf(zx, 0.f); zy = fmaxf(zy, 0.f);
    ((float2*)z)[(long)node*16 + c2] = make_float2(zx, zy);
    // stats: reduce the wave's 4 node-groups, then LDS, then per-slice global
    float sx = zx, sy = zy, qx = zx*zx, qy = zy*zy;
    sx += __shfl_down(sx, 32, 64); sy += __shfl_down(sy, 32, 64);
    qx += __shfl_down(qx, 32, 64); qy += __shfl_down(qy, 32, 64);
    sx += __shfl_down(sx, 16, 64); sy += __shfl_down(sy, 16, 64);
    qx += __shfl_down(qx, 16, 64); qy += __shfl_down(qy, 16, 64);
    if ((tid & 63) < 16) {
        atomicAdd(&stS[2*c2],       sx);
        atomicAdd(&stS[2*c2+1],     sy);
        atomicAdd(&stS[DIM+2*c2],   qx);
        atomicAdd(&stS[DIM+2*c2+1], qy);
    }
    __syncthreads();
    if (tid < 2*DIM)
        atomicAdd(&part[((blockIdx.x & (NSLICE-1))<<6) + tid], stS[tid]);
}

// reduce partial stats -> scale/shift; re-zero partials for next layer
__global__ __launch_bounds__(256) void k_scaleshift(
    float* __restrict__ part,
    const float* __restrict__ gamma, const float* __restrict__ beta,
    int layer, float* __restrict__ ss)
{
    __shared__ float red[4][64];
    __shared__ float totS[64];
    int t = threadIdx.x;
    int ch = t & 63, q = t >> 6;
    float s = 0.f;
    for (int i = q*64; i < q*64 + 64; ++i) s += part[(i<<6) + ch];
    red[q][ch] = s;
    __syncthreads();
    if (t < 64) totS[t] = red[0][t]+red[1][t]+red[2][t]+red[3][t];
    __syncthreads();
    if (t < DIM) {
        float mean = totS[t] * (1.f/N_NODES);
        float var  = totS[DIM+t] * (1.f/N_NODES) - mean*mean;
        float sc = gamma[layer*DIM+t] * rsqrtf(var + 1e-5f);
        ss[t] = sc;
        ss[DIM+t] = beta[layer*DIM+t] - mean*sc;
    }
    for (int i = t; i < NSLICE*64; i += 256) part[i] = 0.f;
}

// Global add pool with BN applied: hg[batch[n]] += BN(z[n])
__global__ __launch_bounds__(256) void k_pool(
    const float* __restrict__ z, const float* __restrict__ ss,
    const int* __restrict__ batch, float* __restrict__ hg)
{
    long g = (long)blockIdx.x*256 + threadIdx.x;
    int node = (int)(g >> 5);
    int c = (int)(g & 31);
    int b = batch[node];
    float v = z[(long)node*DIM + c]*ss[c] + ss[DIM+c];
    atomicAdd(&hg[b*DIM + c], v);
}

// xd = ReLU(hg @ w_fcxd + b) -> xc[:, 0:128]
__global__ __launch_bounds__(128) void k_xd(
    const float* __restrict__ hg, const float* __restrict__ w,
    const float* __restrict__ bias, float* __restrict__ xc)
{
    int b = blockIdx.x, n = threadIdx.x;
    __shared__ float hS[DIM];
    if (n < DIM) hS[n] = hg[b*DIM+n];
    __syncthreads();
    float acc = bias[n];
    #pragma unroll
    for (int r=0; r<DIM; ++r) acc += hS[r]*w[r*OUTD+n];
    xc[b*256 + n] = fmaxf(acc, 0.f);
}

// ---------------- protein branch ----------------

__global__ __launch_bounds__(256) void k_cw_transpose(
    const float* __restrict__ cw, float* __restrict__ cwT)
{
    int g = blockIdx.x*256 + threadIdx.x;   // 256000 total
    int i = g >> 8;
    int j = g & 255;
    int o = j >> 3, k = j & 7;
    cwT[g] = cw[o*(PLEN*KS) + i*KS + k];
}

// LDS budget <= 40 KB -> 4 blocks/CU: sort scratch and embS share one union region
// (sortedS dies at end of bucket-accumulate; embS loaded after it).
__global__ __launch_bounds__(256) void k_conv(
    const int* __restrict__ target, const float* __restrict__ emb,
    const float* __restrict__ cwT, const float* __restrict__ conv_b,
    float* __restrict__ c)
{
    __shared__ float uni[UNIF];              // 14,072 B union region
    __shared__ float Gs[VOCAB*256];          // 26,624 B (reused as output stage)
    __shared__ float cbS[NF];
    int*   sortedS = (int*)uni;              // [0..999]
    int*   cntS    = (int*)uni + 1000;       // [26]
    int*   segS    = (int*)uni + 1026;       // [27]
    int*   curS    = (int*)uni + 1053;       // [26]
    float* embS    = uni;                    // phase 2 (after acc): skewed emb
    int b = blockIdx.x, j = threadIdx.x;
    if (j < VOCAB) cntS[j] = 0;
    if (j < NF) cbS[j] = conv_b[j];
    __syncthreads();
    int tloc[4];
    #pragma unroll
    for (int q=0; q<4; ++q) {
        int i = j + q*256;
        if (i < PLEN) {
            tloc[q] = target[b*PLEN+i];
            atomicAdd(&cntS[tloc[q]], 1);
        } else tloc[q] = -1;
    }
    __syncthreads();
    if (j == 0) {
        int run = 0;
        for (int v=0; v<VOCAB; ++v) { segS[v]=run; run += cntS[v]; }
        segS[VOCAB] = run;
    }
    __syncthreads();
    if (j < VOCAB) curS[j] = segS[j];
    __syncthreads();
    #pragma unroll
    for (int q=0; q<4; ++q) {
        int i = j + q*256;
        if (i < PLEN) {
            int pos = atomicAdd(&curS[tloc[q]], 1);
            sortedS[pos] = i;
        }
    }
    __syncthreads();
    int seg[VOCAB+1];   // keep seg in regs: uni gets overwritten by embS next
    #pragma unroll
    for (int v=0; v<=VOCAB; ++v) seg[v] = segS[v];
    // bucket-accumulate: 8-unroll, 2 independent accumulators
    for (int v=0; v<VOCAB; ++v) {
        int s = seg[v], e2 = seg[v+1];
        float accA = 0.f, accB = 0.f;
        int p = s;
        for (; p+8 <= e2; p += 8) {
            int i0=sortedS[p],   i1=sortedS[p+1], i2=sortedS[p+2], i3=sortedS[p+3];
            int i4=sortedS[p+4], i5=sortedS[p+5], i6=sortedS[p+6], i7=sortedS[p+7];
            accA += (cwT[i0*256+j]+cwT[i1*256+j])+(cwT[i2*256+j]+cwT[i3*256+j]);
            accB += (cwT[i4*256+j]+cwT[i5*256+j])+(cwT[i6*256+j]+cwT[i7*256+j]);
        }
        for (; p<e2; ++p) accA += cwT[sortedS[p]*256+j];
        Gs[v*256+j] = accA + accB;
    }
    __syncthreads();
    // now safe to overwrite union with skewed emb
    for (int i=j; i<VOCAB*EMBD; i+=256) {
        int v = i >> 7, tt = i & 127;
        embS[v*EROW + tt + (tt>>4)] = emb[i];
    }
    __syncthreads();
    int o = j >> 3, pg = j & 7;
    int t0 = pg*16;
    int tcnt = (t0+16 <= CLEN) ? 16 : (CLEN - t0);   // 16 or 9
    float out[16];
    #pragma unroll
    for (int q=0; q<16; ++q) out[q] = cbS[o];
    for (int v=0; v<VOCAB; ++v) {
        float g[KS];
        #pragma unroll
        for (int k=0; k<KS; ++k) g[k] = Gs[v*256 + o*KS + k];
        float e[23];
        const float* ev = &embS[v*EROW + 17*pg];
        #pragma unroll
        for (int m=0; m<23; ++m) e[m] = ev[m + (m>>4)];
        #pragma unroll
        for (int q=0; q<16; ++q) {
            float s = 0.f;
            #pragma unroll
            for (int k=0; k<KS; ++k) s += e[q+k]*g[k];
            out[q] += s;
        }
    }
    __syncthreads();
    float* stage = Gs;
    for (int q=0; q<tcnt; ++q) stage[o*CLEN + t0 + q] = out[q];
    __syncthreads();
    for (int idx=j; idx<FCX; idx+=256)
        c[(long)b*FCX + idx] = stage[idx];
}

// xt: [1024 x 3872] @ [3872 x 128] tiled GEMM with 8-way K-split.
#define XT_KSL 484
#define XT_BK  44
__global__ __launch_bounds__(256) void k_xt(
    const float* __restrict__ c, const float* __restrict__ w,
    const float* __restrict__ bias, float* __restrict__ xc)
{
    __shared__ float cS[32][XT_BK];
    __shared__ float wS[XT_BK][128];
    int b0 = blockIdx.x * 32;
    int ks0 = blockIdx.y * XT_KSL;
    int tid = threadIdx.x;
    int cg = tid >> 5;          // graph group 0..7
    int co = tid & 31;          // col group 0..31
    float acc[4][4];
    #pragma unroll
    for (int i2=0;i2<4;++i2)
      #pragma unroll
      for (int j2=0;j2<4;++j2) acc[i2][j2]=0.f;
    for (int ch=0; ch<11; ++ch) {
        int k0 = ks0 + ch*XT_BK;
        for (int idx=tid; idx<32*XT_BK; idx+=256) {
            int g = idx / XT_BK, kk = idx - g*XT_BK;
            cS[g][kk] = c[(long)(b0+g)*FCX + k0 + kk];
        }
        for (int idx=tid; idx<XT_BK*128; idx+=256) {
            int kk = idx >> 7, n = idx & 127;
            wS[kk][n] = w[(long)(k0+kk)*OUTD + n];
        }
        __syncthreads();
        #pragma unroll 4
        for (int kk=0; kk<XT_BK; ++kk) {
            float cv[4], wv[4];
            #pragma unroll
            for (int q=0;q<4;++q) cv[q] = cS[cg*4+q][kk];
            #pragma unroll
            for (int p=0;p<4;++p) wv[p] = wS[kk][co*4+p];
            #pragma unroll
            for (int q=0;q<4;++q)
              #pragma unroll
              for (int p=0;p<4;++p) acc[q][p] += cv[q]*wv[p];
        }
        __syncthreads();
    }
    #pragma unroll
    for (int q=0;q<4;++q) {
        int g = b0 + cg*4 + q;
        #pragma unroll
        for (int p=0;p<4;++p) {
            int n = co*4 + p;
            float v = acc[q][p];
            if (blockIdx.y == 0) v += bias[n];
            atomicAdd(&xc[g*256 + 128 + n], v);
        }
    }
}

// ---------------- joint head ----------------

__global__ __launch_bounds__(256) void k_fc1(
    const float* __restrict__ xc, const float* __restrict__ w,
    const float* __restrict__ bias, float* __restrict__ y)
{
    __shared__ float xS[4][256];
    int b0 = blockIdx.x*4, n = threadIdx.x;
    #pragma unroll
    for (int q=0; q<4; ++q) xS[q][n] = xc[(b0+q)*256 + n];
    __syncthreads();
    float acc[4][4];
    #pragma unroll
    for (int m=0; m<4; ++m) {
        float bv = bias[m*256+n];
        #pragma unroll
        for (int q=0; q<4; ++q) acc[q][m] = bv;
    }
    for (int r=0; r<256; ++r) {
        float x0=xS[0][r], x1=xS[1][r], x2=xS[2][r], x3=xS[3][r];
        #pragma unroll
        for (int m=0; m<4; ++m) {
            float wv = w[r*1024 + m*256 + n];
            acc[0][m]+=x0*wv; acc[1][m]+=x1*wv; acc[2][m]+=x2*wv; acc[3][m]+=x3*wv;
        }
    }
    #pragma unroll
    for (int q=0; q<4; ++q)
        #pragma unroll
        for (int m=0; m<4; ++m)
            y[(b0+q)*1024 + m*256 + n] = fmaxf(acc[q][m], 0.f);
}

__global__ __launch_bounds__(256) void k_fc2(
    const float* __restrict__ y, const float* __restrict__ w,
    const float* __restrict__ bias, float* __restrict__ y2)
{
    __shared__ float xS[4][1024];
    int b0 = blockIdx.x*4, n = threadIdx.x;
    #pragma unroll
    for (int q=0; q<4; ++q)
        for (int i=n; i<1024; i+=256) xS[q][i] = y[(b0+q)*1024 + i];
    __syncthreads();
    float acc[4];
    #pragma unroll
    for (int q=0; q<4; ++q) acc[q] = bias[n];
    for (int r=0; r<1024; ++r) {
        float wv = w[r*256 + n];
        #pragma unroll
        for (int q=0; q<4; ++q) acc[q] += xS[q][r]*wv;
    }
    #pragma unroll
    for (int q=0; q<4; ++q) y2[(b0+q)*256 + n] = fmaxf(acc[q], 0.f);
}

__global__ __launch_bounds__(256) void k_out(
    const float* __restrict__ y2, const float* __restrict__ w,
    const float* __restrict__ bias, float* __restrict__ out)
{
    int b = blockIdx.x, n = threadIdx.x;
    float v = y2[b*256 + n] * w[n];
    #pragma unroll
    for (int off=32; off; off>>=1) v += __shfl_down(v, off, 64);
    __shared__ float red[4];
    if ((n & 63) == 0) red[n >> 6] = v;
    __syncthreads();
    if (n == 0) out[b] = red[0]+red[1]+red[2]+red[3] + bias[0];
}

// ---------------- launch ----------------

extern "C" void kernel_launch(void* const* d_in, const int* in_sizes, int n_in,
                              void* d_out, int out_size, void* d_ws, size_t ws_size,
                              hipStream_t stream) {
    const float* x      = (const float*)d_in[0];
    const int*   ei     = (const int*)  d_in[1];
    const int*   batch  = (const int*)  d_in[2];
    const int*   target = (const int*)  d_in[3];
    const float* w1a    = (const float*)d_in[4];
    const float* b1a    = (const float*)d_in[5];
    const float* w1b    = (const float*)d_in[6];
    const float* b1b    = (const float*)d_in[7];
    const float* wa     = (const float*)d_in[8];
    const float* ba     = (const float*)d_in[9];
    const float* wb     = (const float*)d_in[10];
    const float* bb     = (const float*)d_in[11];
    const float* gamma  = (const float*)d_in[12];
    const float* beta   = (const float*)d_in[13];
    const float* w_fcxd = (const float*)d_in[14];
    const float* b_fcxd = (const float*)d_in[15];
    const float* emb    = (const float*)d_in[16];
    const float* conv_w = (const float*)d_in[17];
    const float* conv_b = (const float*)d_in[18];
    const float* w_fcxt = (const float*)d_in[19];
    const float* b_fcxt = (const float*)d_in[20];
    const float* w_fc1  = (const float*)d_in[21];
    const float* b_fc1  = (const float*)d_in[22];
    const float* w_fc2  = (const float*)d_in[23];
    const float* b_fc2  = (const float*)d_in[24];
    const float* w_out  = (const float*)d_in[25];
    const float* b_out  = (const float*)d_in[26];

    float* ws      = (float*)d_ws;
    __half* tH     = (__half*)ws;                          // N*32 halfs = 1,048,576 float-slots
    float* z       = ws + 1048576;                         // N*32 floats
    unsigned int* pairs = (unsigned int*)(z + (size_t)N_NODES*DIM);  // E uints
    int*   csr     = (int*)(pairs + N_EDGES);              // E ints
    int*   rowptr  = csr + N_EDGES;                        // N+1 (+pad)
    int*   deg     = rowptr + (N_NODES + 8);               // N
    int*   bsum    = deg + N_NODES;                        // 256
    int*   boffs   = bsum + 256;                           // 256
    int*   bktCnt  = boffs + 256;                          // 256
    int*   bktBase = bktCnt + 256;                         // 257 (+pad)
    int*   bktCur  = bktBase + 264;                        // 256
    float* ss      = (float*)(bktCur + 256);               // 64
    float* hg      = ss + 64;                              // 32768
    float* cwT     = hg + (size_t)NB*DIM;                  // 256000
    float* cbuf    = cwT + 256000;                         // 3964928
    float* xc      = cbuf + (size_t)NB*FCX;                // 262144
    float* y1      = xc + (size_t)NB*256;                  // 1048576
    float* y2      = y1 + (size_t)NB*1024;                 // 262144
    float* part    = y2 + (size_t)NB*256;                  // 256*64

    // ---- CSR build: bucket sort (coalesced) + per-bucket scatter ----
    hipMemsetAsync(bktCnt, 0, 256*sizeof(int), stream);
    hipMemsetAsync(deg, 0, N_NODES*sizeof(int), stream);
    k_bhist<<<N_EDGES/1024, 256, 0, stream>>>(ei, bktCnt);
    k_bscan<<<1, 256, 0, stream>>>(bktCnt, bktBase, bktCur);
    k_bucketA<<<NBKT, 256, 0, stream>>>(ei, bktCur, pairs);
    k_deg<<<N_EDGES/256, 256, 0, stream>>>(ei, deg);
    k_scan1<<<N_NODES/256, 256, 0, stream>>>(deg, rowptr, bsum);
    k_scan2<<<1, 256, 0, stream>>>(bsum, boffs);
    k_scan3<<<N_NODES/256, 256, 0, stream>>>(rowptr, boffs);
    k_fillB<<<NBKT, 256, 0, stream>>>(bktBase, pairs, rowptr, csr);

    // ---- protein branch ----
    hipMemsetAsync(xc, 0, (size_t)NB*256*sizeof(float), stream);
    k_cw_transpose<<<1000, 256, 0, stream>>>(conv_w, cwT);
    k_conv<<<NB, 256, 0, stream>>>(target, emb, cwT, conv_b, cbuf);
    k_xt<<<dim3(32, 8), 256, 0, stream>>>(cbuf, w_fcxt, b_fcxt, xc);

    // ---- GIN layers ----
    hipMemsetAsync(part, 0, NSLICE*64*sizeof(float), stream);
    for (int l=0; l<5; ++l) {
        if (l == 0)
            k_l1_transform<<<N_NODES/256, 256, 0, stream>>>(x, w1a, tH);
        else
            k_transform<<<N_NODES/256, 256, 0, stream>>>(z, ss, wa + (size_t)(l-1)*DIM*DIM, tH);
        const float* bi = (l==0) ? b1a : ba + (size_t)(l-1)*DIM;
        const float* wo = (l==0) ? w1b : wb + (size_t)(l-1)*DIM*DIM;
        const float* bo = (l==0) ? b1b : bb + (size_t)(l-1)*DIM;
        k_gather_mlp<<<N_NODES/16, 256, 0, stream>>>(rowptr, csr, tH, bi, wo, bo, z, part);
        k_scaleshift<<<1, 256, 0, stream>>>(part, gamma, beta, l, ss);
    }

    // ---- pool + drug head ----
    hipMemsetAsync(hg, 0, (size_t)NB*DIM*sizeof(float), stream);
    k_pool<<<(N_NODES*32)/256, 256, 0, stream>>>(z, ss, batch, hg);
    k_xd<<<NB, 128, 0, stream>>>(hg, w_fcxd, b_fcxd, xc);

    // ---- joint head ----
    k_fc1<<<NB/4, 256, 0, stream>>>(xc, w_fc1, b_fc1, y1);
    k_fc2<<<NB/4, 256, 0, stream>>>(y1, w_fc2, b_fc2, y2);
    k_out<<<NB, 256, 0, stream>>>(y2, w_out, b_out, (float*)d_out);
}

// Round 8
// 796.400 us; speedup vs baseline: 3.1987x; 1.1740x over previous
//
#include <hip/hip_runtime.h>
#include <hip/hip_fp16.h>

#define N_NODES 65536
#define N_EDGES 2097152
#define NB      1024
#define FXD     78
#define DIM     32
#define EMBD    128
#define OUTD    128
#define VOCAB   26
#define PLEN    1000
#define KS      8
#define CLEN    121      // EMBD-KS+1
#define NF      32
#define FCX     (NF*CLEN)  // 3872
#define NBKT    256
#define EPB     8192     // edges per bucketA block (N_EDGES/256)
#define NSLICE  256      // stats partial slices
#define EROW    135      // skewed emb row stride: f(t)=t+(t>>4), max f(127)=134
#define UNIF    3518     // union region floats: max(sort scratch 1079 ints, embS 26*135+8)

// ---------------- bucket sort (dst>>8) ----------------

__global__ __launch_bounds__(256) void k_bhist(
    const int* __restrict__ ei, int* __restrict__ bktCnt)
{
    __shared__ int h[NBKT];
    int tid = threadIdx.x;
    h[tid] = 0;
    __syncthreads();
    int base = blockIdx.x*1024;
    #pragma unroll
    for (int q=0; q<4; ++q) {
        int d = ei[N_EDGES + base + q*256 + tid];
        atomicAdd(&h[d>>8], 1);
    }
    __syncthreads();
    atomicAdd(&bktCnt[tid], h[tid]);
}

__global__ __launch_bounds__(256) void k_bscan(
    const int* __restrict__ bktCnt, int* __restrict__ bktBase, int* __restrict__ bktCur)
{
    __shared__ int s[NBKT];
    int t = threadIdx.x;
    int v = bktCnt[t];
    s[t] = v;
    __syncthreads();
    for (int off=1; off<256; off<<=1) {
        int tv = (t >= off) ? s[t-off] : 0;
        __syncthreads();
        s[t] += tv;
        __syncthreads();
    }
    int ex = s[t] - v;
    bktBase[t] = ex;
    bktCur[t] = ex;
    if (t == 255) bktBase[256] = s[255];   // == N_EDGES
}

// LDS-sort 8192 edges by bucket, write packed (dst<<16|src) in coalesced runs
__global__ __launch_bounds__(256) void k_bucketA(
    const int* __restrict__ ei, int* __restrict__ bktCur, unsigned int* __restrict__ pairs)
{
    __shared__ unsigned int raw[EPB];       // 32 KB
    __shared__ unsigned int srt[EPB];       // 32 KB
    __shared__ unsigned char bOf[EPB];      // 8 KB
    __shared__ int hist[NBKT], sc[NBKT], lcur[NBKT], gbase[NBKT];
    int tid = threadIdx.x;
    hist[tid] = 0;
    __syncthreads();
    int eb = blockIdx.x * EPB;
    for (int i=tid; i<EPB; i+=256) {
        int s = ei[eb+i];
        int d = ei[N_EDGES+eb+i];
        raw[i] = ((unsigned int)d<<16) | (unsigned int)s;
        atomicAdd(&hist[d>>8], 1);
    }
    __syncthreads();
    int v = hist[tid];
    sc[tid] = v;
    __syncthreads();
    for (int off=1; off<256; off<<=1) {
        int tv = (tid >= off) ? sc[tid-off] : 0;
        __syncthreads();
        sc[tid] += tv;
        __syncthreads();
    }
    int ex = sc[tid] - v;
    sc[tid] = ex;            // exclusive local base
    lcur[tid] = ex;
    gbase[tid] = atomicAdd(&bktCur[tid], v);
    __syncthreads();
    for (int i=tid; i<EPB; i+=256) {
        unsigned int p = raw[i];
        int k = p >> 24;
        int pos = atomicAdd(&lcur[k], 1);
        srt[pos] = p;
        bOf[pos] = (unsigned char)k;
    }
    __syncthreads();
    for (int i=tid; i<EPB; i+=256) {
        int k = bOf[i];
        pairs[gbase[k] + (i - sc[k])] = srt[i];
    }
}

// per bucket: build rowptr (LDS histogram + scan) and scatter srcs into the
// bucket's contiguous CSR segment. Replaces k_deg + 3 scan kernels.
__global__ __launch_bounds__(256) void k_fillB(
    const int* __restrict__ bktBase, const unsigned int* __restrict__ pairs,
    int* __restrict__ rowptr, int* __restrict__ csr)
{
    __shared__ int hist[256], sc[256], cur[256];
    int b = blockIdx.x, tid = threadIdx.x;
    int node0 = b*256;
    hist[tid] = 0;
    __syncthreads();
    int s = bktBase[b], e = bktBase[b+1];
    for (int i = s + tid; i < e; i += 256)
        atomicAdd(&hist[(pairs[i] >> 16) & 255], 1);
    __syncthreads();
    int v = hist[tid];
    sc[tid] = v;
    __syncthreads();
    for (int off=1; off<256; off<<=1) {
        int tv = (tid >= off) ? sc[tid-off] : 0;
        __syncthreads();
        sc[tid] += tv;
        __syncthreads();
    }
    int base = s + sc[tid] - v;     // exclusive
    rowptr[node0 + tid] = base;
    cur[tid] = base;
    if (b == NBKT-1 && tid == 255) rowptr[N_NODES] = N_EDGES;
    __syncthreads();
    for (int i = s + tid; i < e; i += 256) {
        unsigned int p = pairs[i];
        int pos = atomicAdd(&cur[(p >> 16) & 255], 1);
        csr[pos] = (int)(p & 0xFFFFu);
    }
}

// ---------------- GIN layer kernels ----------------

// Layer-1 transform: t = x @ w1a  (fp16 out)
__global__ __launch_bounds__(256) void k_l1_transform(
    const float* __restrict__ x, const float* __restrict__ w,
    __half* __restrict__ t)
{
    __shared__ float wS[FXD*DIM];
    for (int i = threadIdx.x; i < FXD*DIM; i += 256) wS[i] = w[i];
    __syncthreads();
    int node = blockIdx.x*256 + threadIdx.x;
    float acc[DIM];
    #pragma unroll
    for (int d=0; d<DIM; ++d) acc[d] = 0.f;
    const float* xr = x + (long)node*FXD;
    for (int j=0; j<FXD; ++j) {
        float xv = xr[j];
        #pragma unroll
        for (int d=0; d<DIM; ++d) acc[d] += xv * wS[j*DIM+d];
    }
    union { __half2 h2[16]; uint4 u4[4]; } pk;
    #pragma unroll
    for (int q=0; q<16; ++q) pk.h2[q] = __floats2half2_rn(acc[2*q], acc[2*q+1]);
    uint4* dst4 = (uint4*)(t + (long)node*DIM);
    #pragma unroll
    for (int q=0; q<4; ++q) dst4[q] = pk.u4[q];
}

// Layers 2-5: h = BN(z) via scale/shift; t = h @ w  (fp16 out)
__global__ __launch_bounds__(256) void k_transform(
    const float* __restrict__ z, const float* __restrict__ ss,
    const float* __restrict__ w, __half* __restrict__ t)
{
    __shared__ float wS[DIM*DIM];
    __shared__ float sS[2*DIM];
    for (int i = threadIdx.x; i < DIM*DIM; i += 256) wS[i] = w[i];
    if (threadIdx.x < 2*DIM) sS[threadIdx.x] = ss[threadIdx.x];
    __syncthreads();
    int node = blockIdx.x*256 + threadIdx.x;
    float h[DIM];
    const float4* z4 = (const float4*)(z + (long)node*DIM);
    #pragma unroll
    for (int q=0; q<DIM/4; ++q) {
        float4 v = z4[q];
        h[q*4+0]=v.x; h[q*4+1]=v.y; h[q*4+2]=v.z; h[q*4+3]=v.w;
    }
    #pragma unroll
    for (int d=0; d<DIM; ++d) h[d] = h[d]*sS[d] + sS[DIM+d];
    float acc[DIM];
    #pragma unroll
    for (int d=0; d<DIM; ++d) acc[d] = 0.f;
    #pragma unroll
    for (int j=0; j<DIM; ++j) {
        float hv = h[j];
        #pragma unroll
        for (int d=0; d<DIM; ++d) acc[d] += hv * wS[j*DIM+d];
    }
    union { __half2 h2[16]; uint4 u4[4]; } pk;
    #pragma unroll
    for (int q=0; q<16; ++q) pk.h2[q] = __floats2half2_rn(acc[2*q], acc[2*q+1]);
    uint4* dst4 = (uint4*)(t + (long)node*DIM);
    #pragma unroll
    for (int q=0; q<4; ++q) dst4[q] = pk.u4[q];
}

// Gather (CSR) + self + MLP + ReLU + BN-stats partials.
// 8 lanes/node x 8B (uint2 = 4 halfs): one wave VMEM instr serves 8 edges.
// 32 nodes/block.
__global__ __launch_bounds__(256) void k_gather_mlp(
    const int* __restrict__ rowptr, const int* __restrict__ csr,
    const __half* __restrict__ t,
    const float* __restrict__ bi, const float* __restrict__ wo, const float* __restrict__ bo,
    float* __restrict__ z, float* __restrict__ part)
{
    __shared__ float wS[DIM*DIM];
    __shared__ float bS[2*DIM];
    __shared__ float stS[2*DIM];
    int tid = threadIdx.x;
    for (int i=tid; i<DIM*DIM; i+=256) wS[i]=wo[i];
    if (tid<DIM) bS[tid]=bi[tid];
    else if (tid<2*DIM) bS[tid]=bo[tid-DIM];
    if (tid<2*DIM) stS[tid]=0.f;
    __syncthreads();
    int g = tid >> 3;           // node 0..31 within block
    int l = tid & 7;            // lane in group; owns channels 4l..4l+3
    int node = blockIdx.x*32 + g;
    const uint2* t4 = (const uint2*)t;   // 8B = 4 halfs; 8 entries per row
    uint2 sv = t4[(long)node*8 + l];     // self term
    float2 p0 = __half22float2(*(const __half2*)&sv.x);
    float2 p1 = __half22float2(*(const __half2*)&sv.y);
    float a0=p0.x, a1=p0.y, a2=p1.x, a3=p1.y;
    float c0=0.f, c1=0.f, c2=0.f, c3=0.f;
    int s0 = rowptr[node], s1 = rowptr[node+1];
    int e = s0;
    for (; e+8 <= s1; e+=8) {
        int myIdx = csr[e + l];          // 8 consecutive, coalesced
        #pragma unroll
        for (int k=0; k<8; ++k) {
            int idx = __shfl(myIdx, k, 8);
            uint2 v = t4[(long)idx*8 + l];
            float2 q0 = __half22float2(*(const __half2*)&v.x);
            float2 q1 = __half22float2(*(const __half2*)&v.y);
            if (k & 1) { c0+=q0.x; c1+=q0.y; c2+=q1.x; c3+=q1.y; }
            else       { a0+=q0.x; a1+=q0.y; a2+=q1.x; a3+=q1.y; }
        }
    }
    if (e+4 <= s1) {
        int myIdx = csr[e + (l & 3)];
        #pragma unroll
        for (int k=0; k<4; ++k) {
            int idx = __shfl(myIdx, k, 8);
            uint2 v = t4[(long)idx*8 + l];
            float2 q0 = __half22float2(*(const __half2*)&v.x);
            float2 q1 = __half22float2(*(const __half2*)&v.y);
            if (k & 1) { c0+=q0.x; c1+=q0.y; c2+=q1.x; c3+=q1.y; }
            else       { a0+=q0.x; a1+=q0.y; a2+=q1.x; a3+=q1.y; }
        }
        e += 4;
    }
    for (; e<s1; ++e) {
        uint2 v = t4[(long)csr[e]*8 + l];
        float2 q0 = __half22float2(*(const __half2*)&v.x);
        float2 q1 = __half22float2(*(const __half2*)&v.y);
        a0+=q0.x; a1+=q0.y; a2+=q1.x; a3+=q1.y;
    }
    float ua[4];
    ua[0] = fmaxf(a0+c0 + bS[4*l+0], 0.f);
    ua[1] = fmaxf(a1+c1 + bS[4*l+1], 0.f);
    ua[2] = fmaxf(a2+c2 + bS[4*l+2], 0.f);
    ua[3] = fmaxf(a3+c3 + bS[4*l+3], 0.f);
    float zz[4];
    #pragma unroll
    for (int q=0; q<4; ++q) zz[q] = bS[DIM + 4*l + q];
    const float4* w4 = (const float4*)wS;
    #pragma unroll
    for (int j=0; j<DIM; ++j) {
        float uj = __shfl(ua[j & 3], j >> 2, 8);
        float4 wv = w4[j*8 + l];
        zz[0]+=uj*wv.x; zz[1]+=uj*wv.y; zz[2]+=uj*wv.z; zz[3]+=uj*wv.w;
    }
    #pragma unroll
    for (int q=0; q<4; ++q) zz[q] = fmaxf(zz[q], 0.f);
    ((float4*)z)[(long)node*8 + l] = make_float4(zz[0], zz[1], zz[2], zz[3]);
    // stats: reduce the 8 node-groups of each wave down to 8 lanes
    float sr[4], qr[4];
    #pragma unroll
    for (int q=0; q<4; ++q) { sr[q] = zz[q]; qr[q] = zz[q]*zz[q]; }
    #pragma unroll
    for (int q=0; q<4; ++q) {
        sr[q] += __shfl_down(sr[q], 32, 64); qr[q] += __shfl_down(qr[q], 32, 64);
        sr[q] += __shfl_down(sr[q], 16, 64); qr[q] += __shfl_down(qr[q], 16, 64);
        sr[q] += __shfl_down(sr[q],  8, 64); qr[q] += __shfl_down(qr[q],  8, 64);
    }
    if ((tid & 63) < 8) {
        #pragma unroll
        for (int q=0; q<4; ++q) {
            atomicAdd(&stS[4*l+q],       sr[q]);
            atomicAdd(&stS[DIM+4*l+q],   qr[q]);
        }
    }
    __syncthreads();
    if (tid < 2*DIM)
        atomicAdd(&part[((blockIdx.x & (NSLICE-1))<<6) + tid], stS[tid]);
}

// reduce partial stats -> scale/shift; re-zero partials for next layer
__global__ __launch_bounds__(256) void k_scaleshift(
    float* __restrict__ part,
    const float* __restrict__ gamma, const float* __restrict__ beta,
    int layer, float* __restrict__ ss)
{
    __shared__ float red[4][64];
    __shared__ float totS[64];
    int t = threadIdx.x;
    int ch = t & 63, q = t >> 6;
    float s = 0.f;
    for (int i = q*64; i < q*64 + 64; ++i) s += part[(i<<6) + ch];
    red[q][ch] = s;
    __syncthreads();
    if (t < 64) totS[t] = red[0][t]+red[1][t]+red[2][t]+red[3][t];
    __syncthreads();
    if (t < DIM) {
        float mean = totS[t] * (1.f/N_NODES);
        float var  = totS[DIM+t] * (1.f/N_NODES) - mean*mean;
        float sc = gamma[layer*DIM+t] * rsqrtf(var + 1e-5f);
        ss[t] = sc;
        ss[DIM+t] = beta[layer*DIM+t] - mean*sc;
    }
    for (int i = t; i < NSLICE*64; i += 256) part[i] = 0.f;
}

// Global add pool with BN applied: hg[batch[n]] += BN(z[n])
__global__ __launch_bounds__(256) void k_pool(
    const float* __restrict__ z, const float* __restrict__ ss,
    const int* __restrict__ batch, float* __restrict__ hg)
{
    long g = (long)blockIdx.x*256 + threadIdx.x;
    int node = (int)(g >> 5);
    int c = (int)(g & 31);
    int b = batch[node];
    float v = z[(long)node*DIM + c]*ss[c] + ss[DIM+c];
    atomicAdd(&hg[b*DIM + c], v);
}

// xd = ReLU(hg @ w_fcxd + b) -> xc[:, 0:128]
__global__ __launch_bounds__(128) void k_xd(
    const float* __restrict__ hg, const float* __restrict__ w,
    const float* __restrict__ bias, float* __restrict__ xc)
{
    int b = blockIdx.x, n = threadIdx.x;
    __shared__ float hS[DIM];
    if (n < DIM) hS[n] = hg[b*DIM+n];
    __syncthreads();
    float acc = bias[n];
    #pragma unroll
    for (int r=0; r<DIM; ++r) acc += hS[r]*w[r*OUTD+n];
    xc[b*256 + n] = fmaxf(acc, 0.f);
}

// ---------------- protein branch ----------------

__global__ __launch_bounds__(256) void k_cw_transpose(
    const float* __restrict__ cw, float* __restrict__ cwT)
{
    int g = blockIdx.x*256 + threadIdx.x;   // 256000 total
    int i = g >> 8;
    int j = g & 255;
    int o = j >> 3, k = j & 7;
    cwT[g] = cw[o*(PLEN*KS) + i*KS + k];
}

// LDS budget <= 40 KB -> 4 blocks/CU: sort scratch and embS share one union region
__global__ __launch_bounds__(256) void k_conv(
    const int* __restrict__ target, const float* __restrict__ emb,
    const float* __restrict__ cwT, const float* __restrict__ conv_b,
    float* __restrict__ c)
{
    __shared__ float uni[UNIF];              // 14,072 B union region
    __shared__ float Gs[VOCAB*256];          // 26,624 B (reused as output stage)
    __shared__ float cbS[NF];
    int*   sortedS = (int*)uni;              // [0..999]
    int*   cntS    = (int*)uni + 1000;       // [26]
    int*   segS    = (int*)uni + 1026;       // [27]
    int*   curS    = (int*)uni + 1053;       // [26]
    float* embS    = uni;                    // phase 2 (after acc): skewed emb
    int b = blockIdx.x, j = threadIdx.x;
    if (j < VOCAB) cntS[j] = 0;
    if (j < NF) cbS[j] = conv_b[j];
    __syncthreads();
    int tloc[4];
    #pragma unroll
    for (int q=0; q<4; ++q) {
        int i = j + q*256;
        if (i < PLEN) {
            tloc[q] = target[b*PLEN+i];
            atomicAdd(&cntS[tloc[q]], 1);
        } else tloc[q] = -1;
    }
    __syncthreads();
    if (j == 0) {
        int run = 0;
        for (int v=0; v<VOCAB; ++v) { segS[v]=run; run += cntS[v]; }
        segS[VOCAB] = run;
    }
    __syncthreads();
    if (j < VOCAB) curS[j] = segS[j];
    __syncthreads();
    #pragma unroll
    for (int q=0; q<4; ++q) {
        int i = j + q*256;
        if (i < PLEN) {
            int pos = atomicAdd(&curS[tloc[q]], 1);
            sortedS[pos] = i;
        }
    }
    __syncthreads();
    int seg[VOCAB+1];   // keep seg in regs: uni gets overwritten by embS next
    #pragma unroll
    for (int v=0; v<=VOCAB; ++v) seg[v] = segS[v];
    // bucket-accumulate: 8-unroll, 2 independent accumulators
    for (int v=0; v<VOCAB; ++v) {
        int s = seg[v], e2 = seg[v+1];
        float accA = 0.f, accB = 0.f;
        int p = s;
        for (; p+8 <= e2; p += 8) {
            int i0=sortedS[p],   i1=sortedS[p+1], i2=sortedS[p+2], i3=sortedS[p+3];
            int i4=sortedS[p+4], i5=sortedS[p+5], i6=sortedS[p+6], i7=sortedS[p+7];
            accA += (cwT[i0*256+j]+cwT[i1*256+j])+(cwT[i2*256+j]+cwT[i3*256+j]);
            accB += (cwT[i4*256+j]+cwT[i5*256+j])+(cwT[i6*256+j]+cwT[i7*256+j]);
        }
        for (; p<e2; ++p) accA += cwT[sortedS[p]*256+j];
        Gs[v*256+j] = accA + accB;
    }
    __syncthreads();
    // now safe to overwrite union with skewed emb
    for (int i=j; i<VOCAB*EMBD; i+=256) {
        int v = i >> 7, tt = i & 127;
        embS[v*EROW + tt + (tt>>4)] = emb[i];
    }
    __syncthreads();
    int o = j >> 3, pg = j & 7;
    int t0 = pg*16;
    int tcnt = (t0+16 <= CLEN) ? 16 : (CLEN - t0);   // 16 or 9
    float out[16];
    #pragma unroll
    for (int q=0; q<16; ++q) out[q] = cbS[o];
    for (int v=0; v<VOCAB; ++v) {
        float g[KS];
        #pragma unroll
        for (int k=0; k<KS; ++k) g[k] = Gs[v*256 + o*KS + k];
        float e[23];
        const float* ev = &embS[v*EROW + 17*pg];
        #pragma unroll
        for (int m=0; m<23; ++m) e[m] = ev[m + (m>>4)];
        #pragma unroll
        for (int q=0; q<16; ++q) {
            float s = 0.f;
            #pragma unroll
            for (int k=0; k<KS; ++k) s += e[q+k]*g[k];
            out[q] += s;
        }
    }
    __syncthreads();
    float* stage = Gs;
    for (int q=0; q<tcnt; ++q) stage[o*CLEN + t0 + q] = out[q];
    __syncthreads();
    for (int idx=j; idx<FCX; idx+=256)
        c[(long)b*FCX + idx] = stage[idx];
}

// xt: [1024 x 3872] @ [3872 x 128] tiled GEMM with 8-way K-split.
#define XT_KSL 484
#define XT_BK  44
__global__ __launch_bounds__(256) void k_xt(
    const float* __restrict__ c, const float* __restrict__ w,
    const float* __restrict__ bias, float* __restrict__ xc)
{
    __shared__ float cS[32][XT_BK];
    __shared__ float wS[XT_BK][128];
    int b0 = blockIdx.x * 32;
    int ks0 = blockIdx.y * XT_KSL;
    int tid = threadIdx.x;
    int cg = tid >> 5;          // graph group 0..7
    int co = tid & 31;          // col group 0..31
    float acc[4][4];
    #pragma unroll
    for (int i2=0;i2<4;++i2)
      #pragma unroll
      for (int j2=0;j2<4;++j2) acc[i2][j2]=0.f;
    for (int ch=0; ch<11; ++ch) {
        int k0 = ks0 + ch*XT_BK;
        for (int idx=tid; idx<32*XT_BK; idx+=256) {
            int g = idx / XT_BK, kk = idx - g*XT_BK;
            cS[g][kk] = c[(long)(b0+g)*FCX + k0 + kk];
        }
        for (int idx=tid; idx<XT_BK*128; idx+=256) {
            int kk = idx >> 7, n = idx & 127;
            wS[kk][n] = w[(long)(k0+kk)*OUTD + n];
        }
        __syncthreads();
        #pragma unroll 4
        for (int kk=0; kk<XT_BK; ++kk) {
            float cv[4], wv[4];
            #pragma unroll
            for (int q=0;q<4;++q) cv[q] = cS[cg*4+q][kk];
            #pragma unroll
            for (int p=0;p<4;++p) wv[p] = wS[kk][co*4+p];
            #pragma unroll
            for (int q=0;q<4;++q)
              #pragma unroll
              for (int p=0;p<4;++p) acc[q][p] += cv[q]*wv[p];
        }
        __syncthreads();
    }
    #pragma unroll
    for (int q=0;q<4;++q) {
        int g = b0 + cg*4 + q;
        #pragma unroll
        for (int p=0;p<4;++p) {
            int n = co*4 + p;
            float v = acc[q][p];
            if (blockIdx.y == 0) v += bias[n];
            atomicAdd(&xc[g*256 + 128 + n], v);
        }
    }
}

// ---------------- joint head ----------------

__global__ __launch_bounds__(256) void k_fc1(
    const float* __restrict__ xc, const float* __restrict__ w,
    const float* __restrict__ bias, float* __restrict__ y)
{
    __shared__ float xS[4][256];
    int b0 = blockIdx.x*4, n = threadIdx.x;
    #pragma unroll
    for (int q=0; q<4; ++q) xS[q][n] = xc[(b0+q)*256 + n];
    __syncthreads();
    float acc[4][4];
    #pragma unroll
    for (int m=0; m<4; ++m) {
        float bv = bias[m*256+n];
        #pragma unroll
        for (int q=0; q<4; ++q) acc[q][m] = bv;
    }
    for (int r=0; r<256; ++r) {
        float x0=xS[0][r], x1=xS[1][r], x2=xS[2][r], x3=xS[3][r];
        #pragma unroll
        for (int m=0; m<4; ++m) {
            float wv = w[r*1024 + m*256 + n];
            acc[0][m]+=x0*wv; acc[1][m]+=x1*wv; acc[2][m]+=x2*wv; acc[3][m]+=x3*wv;
        }
    }
    #pragma unroll
    for (int q=0; q<4; ++q)
        #pragma unroll
        for (int m=0; m<4; ++m)
            y[(b0+q)*1024 + m*256 + n] = fmaxf(acc[q][m], 0.f);
}

__global__ __launch_bounds__(256) void k_fc2(
    const float* __restrict__ y, const float* __restrict__ w,
    const float* __restrict__ bias, float* __restrict__ y2)
{
    __shared__ float xS[4][1024];
    int b0 = blockIdx.x*4, n = threadIdx.x;
    #pragma unroll
    for (int q=0; q<4; ++q)
        for (int i=n; i<1024; i+=256) xS[q][i] = y[(b0+q)*1024 + i];
    __syncthreads();
    float acc[4];
    #pragma unroll
    for (int q=0; q<4; ++q) acc[q] = bias[n];
    for (int r=0; r<1024; ++r) {
        float wv = w[r*256 + n];
        #pragma unroll
        for (int q=0; q<4; ++q) acc[q] += xS[q][r]*wv;
    }
    #pragma unroll
    for (int q=0; q<4; ++q) y2[(b0+q)*256 + n] = fmaxf(acc[q], 0.f);
}

__global__ __launch_bounds__(256) void k_out(
    const float* __restrict__ y2, const float* __restrict__ w,
    const float* __restrict__ bias, float* __restrict__ out)
{
    int b = blockIdx.x, n = threadIdx.x;
    float v = y2[b*256 + n] * w[n];
    #pragma unroll
    for (int off=32; off; off>>=1) v += __shfl_down(v, off, 64);
    __shared__ float red[4];
    if ((n & 63) == 0) red[n >> 6] = v;
    __syncthreads();
    if (n == 0) out[b] = red[0]+red[1]+red[2]+red[3] + bias[0];
}

// ---------------- launch ----------------

extern "C" void kernel_launch(void* const* d_in, const int* in_sizes, int n_in,
                              void* d_out, int out_size, void* d_ws, size_t ws_size,
                              hipStream_t stream) {
    const float* x      = (const float*)d_in[0];
    const int*   ei     = (const int*)  d_in[1];
    const int*   batch  = (const int*)  d_in[2];
    const int*   target = (const int*)  d_in[3];
    const float* w1a    = (const float*)d_in[4];
    const float* b1a    = (const float*)d_in[5];
    const float* w1b    = (const float*)d_in[6];
    const float* b1b    = (const float*)d_in[7];
    const float* wa     = (const float*)d_in[8];
    const float* ba     = (const float*)d_in[9];
    const float* wb     = (const float*)d_in[10];
    const float* bb     = (const float*)d_in[11];
    const float* gamma  = (const float*)d_in[12];
    const float* beta   = (const float*)d_in[13];
    const float* w_fcxd = (const float*)d_in[14];
    const float* b_fcxd = (const float*)d_in[15];
    const float* emb    = (const float*)d_in[16];
    const float* conv_w = (const float*)d_in[17];
    const float* conv_b = (const float*)d_in[18];
    const float* w_fcxt = (const float*)d_in[19];
    const float* b_fcxt = (const float*)d_in[20];
    const float* w_fc1  = (const float*)d_in[21];
    const float* b_fc1  = (const float*)d_in[22];
    const float* w_fc2  = (const float*)d_in[23];
    const float* b_fc2  = (const float*)d_in[24];
    const float* w_out  = (const float*)d_in[25];
    const float* b_out  = (const float*)d_in[26];

    float* ws      = (float*)d_ws;
    __half* tH     = (__half*)ws;                          // N*32 halfs = 1,048,576 float-slots
    float* z       = ws + 1048576;                         // N*32 floats
    unsigned int* pairs = (unsigned int*)(z + (size_t)N_NODES*DIM);  // E uints
    int*   csr     = (int*)(pairs + N_EDGES);              // E ints
    int*   rowptr  = csr + N_EDGES;                        // N+1 (+pad)
    int*   bktCnt  = rowptr + (N_NODES + 8);               // 256
    int*   bktBase = bktCnt + 256;                         // 257 (+pad)
    int*   bktCur  = bktBase + 264;                        // 256
    float* ss      = (float*)(bktCur + 256);               // 64
    float* hg      = ss + 64;                              // 32768
    float* cwT     = hg + (size_t)NB*DIM;                  // 256000
    float* cbuf    = cwT + 256000;                         // 3964928
    float* xc      = cbuf + (size_t)NB*FCX;                // 262144
    float* y1      = xc + (size_t)NB*256;                  // 1048576
    float* y2      = y1 + (size_t)NB*1024;                 // 262144
    float* part    = y2 + (size_t)NB*256;                  // 256*64

    // ---- CSR build: bucket sort (coalesced) + fused rowptr/scatter ----
    hipMemsetAsync(bktCnt, 0, 256*sizeof(int), stream);
    k_bhist<<<N_EDGES/1024, 256, 0, stream>>>(ei, bktCnt);
    k_bscan<<<1, 256, 0, stream>>>(bktCnt, bktBase, bktCur);
    k_bucketA<<<NBKT, 256, 0, stream>>>(ei, bktCur, pairs);
    k_fillB<<<NBKT, 256, 0, stream>>>(bktBase, pairs, rowptr, csr);

    // ---- protein branch ----
    hipMemsetAsync(xc, 0, (size_t)NB*256*sizeof(float), stream);
    k_cw_transpose<<<1000, 256, 0, stream>>>(conv_w, cwT);
    k_conv<<<NB, 256, 0, stream>>>(target, emb, cwT, conv_b, cbuf);
    k_xt<<<dim3(32, 8), 256, 0, stream>>>(cbuf, w_fcxt, b_fcxt, xc);

    // ---- GIN layers ----
    hipMemsetAsync(part, 0, NSLICE*64*sizeof(float), stream);
    for (int l=0; l<5; ++l) {
        if (l == 0)
            k_l1_transform<<<N_NODES/256, 256, 0, stream>>>(x, w1a, tH);
        else
            k_transform<<<N_NODES/256, 256, 0, stream>>>(z, ss, wa + (size_t)(l-1)*DIM*DIM, tH);
        const float* bi = (l==0) ? b1a : ba + (size_t)(l-1)*DIM;
        const float* wo = (l==0) ? w1b : wb + (size_t)(l-1)*DIM*DIM;
        const float* bo = (l==0) ? b1b : bb + (size_t)(l-1)*DIM;
        k_gather_mlp<<<N_NODES/32, 256, 0, stream>>>(rowptr, csr, tH, bi, wo, bo, z, part);
        k_scaleshift<<<1, 256, 0, stream>>>(part, gamma, beta, l, ss);
    }

    // ---- pool + drug head ----
    hipMemsetAsync(hg, 0, (size_t)NB*DIM*sizeof(float), stream);
    k_pool<<<(N_NODES*32)/256, 256, 0, stream>>>(z, ss, batch, hg);
    k_xd<<<NB, 128, 0, stream>>>(hg, w_fcxd, b_fcxd, xc);

    // ---- joint head ----
    k_fc1<<<NB/4, 256, 0, stream>>>(xc, w_fc1, b_fc1, y1);
    k_fc2<<<NB/4, 256, 0, stream>>>(y1, w_fc2, b_fc2, y2);
    k_out<<<NB, 256, 0, stream>>>(y2, w_out, b_out, (float*)d_out);
}